// Round 26
// baseline (1802.207 us; speedup 1.0000x reference)
//
#include <hip/hip_runtime.h>
#include <math.h>

namespace {

constexpr int V_  = 32000;
constexpr int K_  = 32;
constexpr int D_  = 256;
constexpr int T_  = 128;
constexpr int B_  = 128;
constexpr int M_  = 16;
constexpr int D4_ = 1024;
constexpr int TD_ = T_ - 1;      // 127
constexpr int R_  = B_ * TD_;    // 16256
constexpr int NCH_ = 8;          // lse grid-y chunks

typedef __attribute__((ext_vector_type(8))) short short8;
typedef __attribute__((ext_vector_type(4))) float f32x4;
typedef __attribute__((ext_vector_type(2))) float f32x2;

// fast reciprocal (v_rcp_f32, ~1ulp; rcp(inf)=0 keeps sig/tanh saturation exact)
__device__ __forceinline__ float d_rcp(float x){
#if __has_builtin(__builtin_amdgcn_rcpf)
  return __builtin_amdgcn_rcpf(x);
#else
  return 1.0f / x;
#endif
}
__device__ __forceinline__ float d_sig(float x){
  return d_rcp(1.0f + __expf(-x));
}
__device__ __forceinline__ float d_tanh(float x){
  float e = __expf(2.0f*x);          // inf-safe: rcp(inf)=0 -> tanh=1
  return 1.0f - 2.0f*d_rcp(e + 1.0f);
}
__device__ __forceinline__ unsigned short f2bf(float f){  // RNE fp32->bf16
  unsigned int x = __float_as_uint(f);
  unsigned int r = (x + 0x7FFFu + ((x>>16)&1u)) >> 16;
  return (unsigned short)r;
}

// fp32 -> OCP e4m3 (RNE, denormal-correct; clamps at 448)  [software path]
__device__ __forceinline__ unsigned f2fp8(float f){
  unsigned u = __float_as_uint(f);
  unsigned s = (u>>31)<<7;
  float a = fabsf(f);
  if (a < 0.015625f){
    int m = (int)rintf(a*512.0f);
    if (m >= 8) return s | 0x08u;
    return s | (unsigned)m;
  }
  unsigned t = u & 0x7FFFFFFFu;
  t += 0x7FFFFu + ((t>>20)&1u);
  int E = (int)(t>>23) - 127 + 7;
  if (E >= 16) return s | 0x7Eu;
  return s | ((unsigned)E<<3) | ((t>>20)&7u);
}

// pack 4 floats -> 4x fp8 (HW v_cvt_pk_fp8_f32 on gfx950; sw fallback identical)
__device__ __forceinline__ unsigned pack4_fp8(float a, float b, float c, float d){
#if __has_builtin(__builtin_amdgcn_cvt_pk_fp8_f32)
  unsigned r = (unsigned)__builtin_amdgcn_cvt_pk_fp8_f32(a, b, 0, false);
  r = (unsigned)__builtin_amdgcn_cvt_pk_fp8_f32(c, d, (int)r, true);
  return r;
#else
  return f2fp8(a) | (f2fp8(b)<<8) | (f2fp8(c)<<16) | (f2fp8(d)<<24);
#endif
}
__device__ __forceinline__ unsigned char f2fp8_b(float f){  // single byte, HW path
#if __has_builtin(__builtin_amdgcn_cvt_pk_fp8_f32)
  return (unsigned char)(__builtin_amdgcn_cvt_pk_fp8_f32(f, f, 0, false) & 0xFF);
#else
  return (unsigned char)f2fp8(f);
#endif
}

// 4x fp8 (packed u32) -> 4x f32  [validated r8/r10: absmax 0.0]
__device__ __forceinline__ void cvt4_fp8(unsigned w, float* o){
#if __has_builtin(__builtin_amdgcn_cvt_pk_f32_fp8)
  f32x2 lo = __builtin_amdgcn_cvt_pk_f32_fp8(w, false);
  f32x2 hi = __builtin_amdgcn_cvt_pk_f32_fp8(w, true);
  o[0]=lo.x; o[1]=lo.y; o[2]=hi.x; o[3]=hi.y;
#else
  #pragma unroll
  for (int j = 0; j < 4; j++){
    unsigned b = (w>>(8*j)) & 0xFFu;
    unsigned e = (b>>3) & 15u, m = b & 7u;
    float mag = e ? __uint_as_float(((e+120u)<<23)|(m<<20)) : (float)m*0.001953125f;
    o[j] = (b & 0x80u) ? -mag : mag;
  }
#endif
}

// ---------------- prep ----------------
// fused sent_emb + kv_emb: blocks [0,B*T) sent rows, rest kv rows
__global__ void k_emb2(const int* __restrict__ sent, const int* __restrict__ keys,
                       const int* __restrict__ vals, const float* __restrict__ emb,
                       float* __restrict__ sent_emb, float* __restrict__ kv){
  int bid = blockIdx.x, tid = threadIdx.x;
  if (bid < B_*T_){
    sent_emb[(size_t)bid*256 + tid] = emb[(size_t)sent[bid]*D_ + tid];
  } else {
    int r = bid - B_*T_;
    kv[(size_t)r*256 + tid] = emb[(size_t)keys[r]*D_ + tid]
                            + emb[(size_t)vals[r]*D_ + tid];
  }
}

__global__ void k_kv_enc(const int* __restrict__ keys, const float* __restrict__ kv,
                         float* __restrict__ out){
  int idx = blockIdx.x*256 + threadIdx.x;     // B*D
  int b = idx >> 8, d = idx & 255;
  float s = 0.0f, c = 0.0f;
  for (int m = 0; m < M_; m++){
    if (keys[b*M_+m] != 0){ s += kv[(size_t)(b*M_+m)*D_ + d]; c += 1.0f; }
  }
  out[idx] = s / c;
}

// one block per row: C[r][j] = sum_d A[r][d]*W[d][j] + bias
__global__ void k_rowgemm(const float* __restrict__ A, const float* __restrict__ W,
                          const float* __restrict__ bias, float* __restrict__ C,
                          int inner, int cols){
  __shared__ float sA[256];
  int r = blockIdx.x;
  if ((int)threadIdx.x < inner) sA[threadIdx.x] = A[(size_t)r*inner + threadIdx.x];
  __syncthreads();
  for (int j = threadIdx.x; j < cols; j += blockDim.x){
    float acc = bias ? bias[j] : 0.0f;
    #pragma unroll 4
    for (int d = 0; d < inner; d++) acc += sA[d]*W[(size_t)d*cols + j];
    C[(size_t)r*cols + j] = acc;
  }
}

// two outputs from one staged A row (h0/c0, memk/memk2)
__global__ void k_rowgemm2(const float* __restrict__ A,
                           const float* __restrict__ W1, const float* __restrict__ b1,
                           float* __restrict__ C1,
                           const float* __restrict__ W2, const float* __restrict__ b2,
                           float* __restrict__ C2, int inner, int cols){
  __shared__ float sA[256];
  int r = blockIdx.x;
  if ((int)threadIdx.x < inner) sA[threadIdx.x] = A[(size_t)r*inner + threadIdx.x];
  __syncthreads();
  for (int j = threadIdx.x; j < cols; j += blockDim.x){
    float a1 = b1 ? b1[j] : 0.0f;
    float a2 = b2 ? b2[j] : 0.0f;
    #pragma unroll 4
    for (int d = 0; d < inner; d++){
      float a = sA[d];
      a1 += a*W1[(size_t)d*cols + j];
      a2 += a*W2[(size_t)d*cols + j];
    }
    C1[(size_t)r*cols + j] = a1;
    C2[(size_t)r*cols + j] = a2;
  }
}

// ---------------- transpose + fp8: W[256][ldw-span] -> Wt8[cols][256] bytes
__global__ __launch_bounds__(256) void k_wt8(const float* __restrict__ W,
                                             unsigned char* __restrict__ Wt8, int ldw){
  __shared__ unsigned char st[64][272];
  int tid = threadIdx.x; size_t c0 = (size_t)blockIdx.x*64;
  for (int l = tid; l < 64*256; l += 256){
    int k = l >> 6, c = l & 63;
    st[c][k] = f2fp8_b(W[(size_t)k*ldw + c0 + c]);
  }
  __syncthreads();
  for (int l = tid; l < 64*16; l += 256){
    int c = l >> 4, s = l & 15;
    *reinterpret_cast<uint4*>(&Wt8[(c0+c)*256 + s*16]) =
      *reinterpret_cast<const uint4*>(&st[c][s*16]);
  }
}

// two Whh transposes in one launch (32 blocks)
__global__ __launch_bounds__(256) void k_wt8_2(const float* __restrict__ W1,
    const float* __restrict__ W2, unsigned char* __restrict__ O1,
    unsigned char* __restrict__ O2, int ldw){
  __shared__ unsigned char st[64][272];
  const float* W = (blockIdx.x < 16) ? W1 : W2;
  unsigned char* O = (blockIdx.x < 16) ? O1 : O2;
  int tid = threadIdx.x; size_t c0 = (size_t)(blockIdx.x & 15)*64;
  for (int l = tid; l < 64*256; l += 256){
    int k = l >> 6, c = l & 63;
    st[c][k] = f2fp8_b(W[(size_t)k*ldw + c0 + c]);
  }
  __syncthreads();
  for (int l = tid; l < 64*16; l += 256){
    int c = l >> 4, s = l & 15;
    *reinterpret_cast<uint4*>(&O[(c0+c)*256 + s*16]) =
      *reinterpret_cast<const uint4*>(&st[c][s*16]);
  }
}

// two bf16 1024-col transposes in one launch (32 blocks)
__global__ __launch_bounds__(256) void k_wtg2(const float* __restrict__ W1,
    const float* __restrict__ W2, unsigned short* __restrict__ O1,
    unsigned short* __restrict__ O2, int ldw){
  __shared__ unsigned short st[64][264];
  const float* W = (blockIdx.x < 16) ? W1 : W2;
  unsigned short* O = (blockIdx.x < 16) ? O1 : O2;
  int tid = threadIdx.x; size_t c0 = (size_t)(blockIdx.x & 15)*64;
  for (int l = tid; l < 64*256; l += 256){
    int k = l >> 6, c = l & 63;
    st[c][k] = f2bf(W[(size_t)k*ldw + c0 + c]);
  }
  __syncthreads();
  for (int l = tid; l < 64*32; l += 256){
    int c = l >> 5, s = l & 31;
    *reinterpret_cast<uint4*>(&O[(c0+c)*256 + s*8]) =
      *reinterpret_cast<const uint4*>(&st[c][s*8]);
  }
}

// six 256x256 transposes in one launch (24 blocks)
__global__ __launch_bounds__(256) void k_wtg6(
    const float* s0, const float* s1, const float* s2,
    const float* s3, const float* s4, const float* s5,
    unsigned short* d0, unsigned short* d1, unsigned short* d2,
    unsigned short* d3, unsigned short* d4, unsigned short* d5){
  __shared__ unsigned short st[64][264];
  int m = blockIdx.x >> 2, blk = blockIdx.x & 3;
  const float* S; unsigned short* D;
  if      (m == 0){ S = s0; D = d0; }
  else if (m == 1){ S = s1; D = d1; }
  else if (m == 2){ S = s2; D = d2; }
  else if (m == 3){ S = s3; D = d3; }
  else if (m == 4){ S = s4; D = d4; }
  else            { S = s5; D = d5; }
  int tid = threadIdx.x; size_t c0 = (size_t)blk*64;
  for (int l = tid; l < 64*256; l += 256){
    int k = l >> 6, c = l & 63;
    st[c][k] = f2bf(S[(size_t)k*256 + c0 + c]);
  }
  __syncthreads();
  for (int l = tid; l < 64*32; l += 256){
    int c = l >> 5, s = l & 31;
    *reinterpret_cast<uint4*>(&D[(c0+c)*256 + s*8]) =
      *reinterpret_cast<const uint4*>(&st[c][s*8]);
  }
}

// ---------------- generic bf16-MFMA GEMM (passing since r3)
// TMD: 0 = row-major C; else C row permuted r=b*TMD+t -> (t*B_+b) (time-major
// scan input; TMD = T_ for encoder rows b*128+t, TD_ for decoder rows b*127+t)
template<int G1, int G2, int HALVES, int CPB, bool BIAS, int TMD>
__global__ __launch_bounds__(512) void k_gemm(
    const float* __restrict__ A1, const float* __restrict__ A2,
    const unsigned short* __restrict__ W1, const unsigned short* __restrict__ W2,
    const float* __restrict__ bias, float* __restrict__ C, int cols,
    const float* __restrict__ drop, const float* __restrict__ xl){
  __shared__ unsigned short Al[128*256];
  __shared__ unsigned short Wl[64*256];
  int tid = threadIdx.x;
  int row0 = blockIdx.x*128;
  int w = tid >> 6, l = tid & 63;
  int arow = 16*w + (l & 15);
  float xlv = 0.0f;
  if constexpr (G1==1) xlv = xl[0];
  f32x4 acc[CPB][4];
  #pragma unroll
  for (int cc=0;cc<CPB;cc++)
    #pragma unroll
    for (int nf=0;nf<4;nf++) acc[cc][nf] = (f32x4){0.f,0.f,0.f,0.f};

  for (int h = 0; h < HALVES; h++){
    const float* Asrc = h ? A2 : A1;
    const unsigned short* Wt = h ? W2 : W1;
    int gm = h ? G2 : G1;
    __syncthreads();
    #pragma unroll
    for (int q = 0; q < 8; q++){
      int u = tid + q*512;
      int row = u >> 5, slot = u & 31;
      int r = row0 + row;
      float vals[8];
      if (gm == 0){
        const float* s = Asrc + (size_t)r*256 + slot*8;
        #pragma unroll
        for (int j=0;j<8;j++) vals[j] = s[j];
      } else if (gm == 1){
        int b = r / TD_, t = r - b*TD_;
        int bt = b*T_ + t;
        float wm = (drop[bt] > xlv) ? 1.0f : 0.0f;
        const float* se = A1 + (size_t)bt*256 + slot*8;
        const float* zs = A2 + (size_t)bt*256 + slot*8;
        #pragma unroll
        for (int j=0;j<8;j++) vals[j] = se[j]*wm + (t>0 ? zs[j] : 0.0f);
      } else {
        int b = r / TD_, t = r - b*TD_;
        const float* s = Asrc + (size_t)(b*T_ + t + 1)*256 + slot*8;
        #pragma unroll
        for (int j=0;j<8;j++) vals[j] = s[j];
      }
      union { unsigned short us[8]; uint4 v4; } tu;
      #pragma unroll
      for (int j=0;j<8;j++) tu.us[j] = f2bf(vals[j]);
      int dst = row*512 + ((slot*16) ^ ((row&7)<<4));
      *reinterpret_cast<uint4*>(reinterpret_cast<char*>(Al) + dst) = tu.v4;
    }
    __syncthreads();
    short8 afr[8];
    #pragma unroll
    for (int k0 = 0; k0 < 8; k0++){
      int kb = k0*64 + ((l>>4)*16);
      afr[k0] = *reinterpret_cast<const short8*>(
          reinterpret_cast<const char*>(Al) + arow*512 + (kb ^ ((arow&7)<<4)));
    }
    for (int cc = 0; cc < CPB; cc++){
      int col0 = (blockIdx.y*CPB + cc)*64;
      __syncthreads();
      #pragma unroll
      for (int q = 0; q < 4; q++){
        int u = tid + q*512;
        int c = u >> 5, slot = u & 31;
        int dst = c*512 + ((slot*16) ^ ((c&7)<<4));
        *reinterpret_cast<uint4*>(reinterpret_cast<char*>(Wl) + dst) =
          *reinterpret_cast<const uint4*>(
              reinterpret_cast<const char*>(Wt) + (size_t)(col0+c)*512 + slot*16);
      }
      __syncthreads();
      #pragma unroll
      for (int k0 = 0; k0 < 8; k0++){
        int kb = k0*64 + ((l>>4)*16);
        #pragma unroll
        for (int nf = 0; nf < 4; nf++){
          int bc = nf*16 + (l & 15);
          short8 bfr = *reinterpret_cast<const short8*>(
              reinterpret_cast<const char*>(Wl) + bc*512 + (kb ^ ((bc&7)<<4)));
          acc[cc][nf] = __builtin_amdgcn_mfma_f32_16x16x32_bf16(afr[k0], bfr, acc[cc][nf], 0, 0, 0);
        }
      }
    }
  }
  #pragma unroll
  for (int cc = 0; cc < CPB; cc++){
    int col0 = (blockIdx.y*CPB + cc)*64;
    #pragma unroll
    for (int nf = 0; nf < 4; nf++){
      int col = col0 + nf*16 + (l & 15);
      float bv = BIAS ? bias[col] : 0.0f;
      #pragma unroll
      for (int r4 = 0; r4 < 4; r4++){
        int row = row0 + 16*w + (l>>4)*4 + r4;
        size_t orow;
        if constexpr (TMD == 0){
          orow = (size_t)row;
        } else {
          int bb = row / TMD, tt = row - bb*TMD;
          orow = (size_t)tt*B_ + bb;
        }
        C[orow*cols + col] = acc[cc][nf][r4] + bv;
      }
    }
  }
}

// ---------------- LSTM scan v16 (r23/r25-EXACT, proven 328us)
__global__ __launch_bounds__(1024, 4) void k_lstm12(
    const float* __restrict__ xW,          // [NT][B][1024] time-major
    const unsigned char* __restrict__ Wt,  // WhhT8 [1024][256] fp8
    const float* __restrict__ h0, const float* __restrict__ c0,
    float* __restrict__ Hout,              // [B][NT][256]
    int NT){
  __shared__ unsigned char Wl[512*256];    // cols 0..511 (gates i,f), swizzled
  __shared__ unsigned char Ahl[2][16*256]; // h fp8, double buffer (8KB)
  int g0 = blockIdx.x;                     // batches 16g0..16g0+15
  int tid = threadIdx.x;
  int w = tid >> 6, l = tid & 63;          // wave 0..15, lane

  // stage Wl (cols 0..511) with the k_lse8 swizzle
  for (int i = tid; i < 512*16; i += 1024){
    int c = i >> 4, s16 = i & 15;
    int dst = c*256 + ((s16*16) ^ ((c&7)<<4));
    *reinterpret_cast<uint4*>(&Wl[dst]) =
      *reinterpret_cast<const uint4*>(&Wt[(size_t)c*256 + s16*16]);
  }
  // stage initial h fp8 into Ahl[0]
  if (tid < 256){
    int row = tid >> 4, gblk = tid & 15;
    unsigned pk[4];
    #pragma unroll
    for (int g = 0; g < 4; g++){
      float v0 = h0 ? h0[(size_t)(g0*16+row)*256 + gblk*16 + 4*g + 0] : 0.0f;
      float v1 = h0 ? h0[(size_t)(g0*16+row)*256 + gblk*16 + 4*g + 1] : 0.0f;
      float v2 = h0 ? h0[(size_t)(g0*16+row)*256 + gblk*16 + 4*g + 2] : 0.0f;
      float v3 = h0 ? h0[(size_t)(g0*16+row)*256 + gblk*16 + 4*g + 3] : 0.0f;
      pk[g] = pack4_fp8(v0, v1, v2, v3);
    }
    int dst = row*256 + ((gblk*16) ^ ((row&7)<<4));
    *reinterpret_cast<uint4*>(&Ahl[0][dst]) = *reinterpret_cast<const uint4*>(pk);
  }
  int cb = 16*w + (l & 15);                // this lane's unit (0..255)
  int arow = l & 15;
  // c state: lane owns unit cb, batches (l>>4)*4+r
  float creg[4];
  #pragma unroll
  for (int r = 0; r < 4; r++)
    creg[r] = c0 ? c0[(size_t)(g0*16 + (l>>4)*4 + r)*256 + cb] : 0.0f;

  // t-invariant addresses, kept live in registers
  int aoff[8], b0off[8], b1off[8];
  #pragma unroll
  for (int k0 = 0; k0 < 8; k0++){
    int kb = k0*32 + ((l>>4)*8);
    aoff[k0]  = arow*256 + (kb ^ ((arow&7)<<4));
    b0off[k0] = cb*256 + (kb ^ ((cb&7)<<4));
    b1off[k0] = (256+cb)*256 + (kb ^ ((cb&7)<<4));
  }
  const unsigned char* wg2 = Wt + (size_t)(512+cb)*256 + ((l>>4)*8);
  const unsigned char* wg3 = Wt + (size_t)(768+cb)*256 + ((l>>4)*8);
  int astore[4];
  const float* xb[4];
  float* hp[4];
  #pragma unroll
  for (int r = 0; r < 4; r++){
    int batch = (l>>4)*4 + r;
    astore[r] = batch*256 + ((cb & 0xF0) ^ ((batch&7)<<4)) + (cb & 15);
    xb[r] = xW + (size_t)(g0*16 + batch)*1024 + cb;
    hp[r] = Hout + (size_t)(g0*16 + batch)*NT*256 + cb;
  }
  __syncthreads();

  // prefetch t=0 xW into registers
  float xn[4][4];
  #pragma unroll
  for (int gt = 0; gt < 4; gt++)
    #pragma unroll
    for (int r = 0; r < 4; r++)
      xn[gt][r] = xb[r][gt*256];

  for (int t = 0; t < NT; t++){
    int cur = t & 1, nxt = cur ^ 1;
    // acc init = prefetched xW (MFMA C-in); [gate]
    f32x4 acc[4];
    #pragma unroll
    for (int gt = 0; gt < 4; gt++)
      #pragma unroll
      for (int r = 0; r < 4; r++)
        acc[gt][r] = xn[gt][r];
    // issue next step's xW loads now; they retire under the K-loop + cell
    if (t + 1 < NT){
      #pragma unroll
      for (int r = 0; r < 4; r++) xb[r] += B_*1024;
      #pragma unroll
      for (int gt = 0; gt < 4; gt++)
        #pragma unroll
        for (int r = 0; r < 4; r++)
          xn[gt][r] = xb[r][gt*256];
    }
    // K loop: 8 x 32
    const unsigned char* Ac = Ahl[cur];
    #pragma unroll
    for (int k0 = 0; k0 < 8; k0++){
      long long afr = *reinterpret_cast<const long long*>(Ac + aoff[k0]);
      long long b0 = *reinterpret_cast<const long long*>(Wl + b0off[k0]);
      long long b1 = *reinterpret_cast<const long long*>(Wl + b1off[k0]);
      long long b2 = *reinterpret_cast<const long long*>(wg2 + k0*32);
      long long b3 = *reinterpret_cast<const long long*>(wg3 + k0*32);
      acc[0] = __builtin_amdgcn_mfma_f32_16x16x32_fp8_fp8(afr, b0, acc[0], 0, 0, 0);
      acc[1] = __builtin_amdgcn_mfma_f32_16x16x32_fp8_fp8(afr, b1, acc[1], 0, 0, 0);
      acc[2] = __builtin_amdgcn_mfma_f32_16x16x32_fp8_fp8(afr, b2, acc[2], 0, 0, 0);
      acc[3] = __builtin_amdgcn_mfma_f32_16x16x32_fp8_fp8(afr, b3, acc[3], 0, 0, 0);
    }
    // cell update (C/D layout: col=l&15, row=(l>>4)*4+r) — 4 cells/lane
    #pragma unroll
    for (int r = 0; r < 4; r++){
      float vi = acc[0][r], vf = acc[1][r];
      float vg = acc[2][r], vo = acc[3][r];
      float cn = d_sig(vf)*creg[r] + d_sig(vi)*d_tanh(vg);
      float hn = d_sig(vo)*d_tanh(cn);
      creg[r] = cn;
      Ahl[nxt][astore[r]] = f2fp8_b(hn);
      hp[r][0] = hn;
      hp[r] += 256;
    }
    __syncthreads();   // Ahl[nxt] complete before next step's reads
  }
}

// ---------------- phi = enc_out @ crf_W + b  (time-major [t][b][k])
__global__ __launch_bounds__(256) void k_phi(const float* __restrict__ H,
    const float* __restrict__ Wc, const float* __restrict__ bc,
    float* __restrict__ phi){
  __shared__ float sH[8][256];
  int tid = threadIdx.x; int rl = tid >> 5, j = tid & 31;
  int r0 = blockIdx.x*8;
  for (int i = tid; i < 512; i += 256){
    int rr = i >> 6, c4 = i & 63;
    *reinterpret_cast<float4*>(&sH[rr][c4*4]) =
      *reinterpret_cast<const float4*>(&H[(size_t)(r0+rr)*256 + c4*4]);
  }
  __syncthreads();
  int r = r0 + rl;                    // r = b*128 + t
  int b = r >> 7, t = r & 127;
  float acc = bc[j];
  #pragma unroll 4
  for (int d = 0; d < 256; d++) acc += sH[rl][d]*Wc[d*K_ + j];
  phi[(size_t)t*B_*K_ + b*K_ + j] = acc;
}

// ---------------- fused z_logits + lpz (LDS row staging)
__global__ __launch_bounds__(256) void k_zlp(const float* __restrict__ A,
    const float* __restrict__ Wz, const float* __restrict__ bz,
    const int* __restrict__ zids, float* __restrict__ lpz){
  __shared__ float sA[8][256];
  int tid = threadIdx.x; int rl = tid >> 5, j = tid & 31;
  int r0 = blockIdx.x*8;
  for (int i = tid; i < 512; i += 256){
    int rr = i >> 6, c4 = i & 63;
    *reinterpret_cast<float4*>(&sA[rr][c4*4]) =
      *reinterpret_cast<const float4*>(&A[(size_t)(r0+rr)*256 + c4*4]);
  }
  __syncthreads();
  int r = r0 + rl;
  float acc = bz[j];
  #pragma unroll 4
  for (int d = 0; d < 256; d++) acc += sA[rl][d]*Wz[d*K_ + j];
  float m = acc;
  #pragma unroll
  for (int off=16; off; off>>=1) m = fmaxf(m, __shfl_xor(m, off, 32));
  float e = __expf(acc - m), E = e;
  #pragma unroll
  for (int off=16; off; off>>=1) E += __shfl_xor(E, off, 32);
  int b = r / TD_, t = r - b*TD_;
  int tz = zids[b*T_ + t + 1];
  float vtz = __shfl(acc, tz, 32);
  if (j == 0) lpz[r] = vtz - (m + logf(E));
}

// ---------------- CRF forward scan + entropy (double-buffered, 1 barrier/step)
__global__ __launch_bounds__(1024) void k_crf(
    const float* __restrict__ phi, const float* __restrict__ trans,
    const int* __restrict__ lens, float* __restrict__ alphas,
    float* __restrict__ ent_b){
  __shared__ float sal[2][K_], sH[2][K_];
  int tid = threadIdx.x, b = blockIdx.x;
  int i = tid & 31, j = tid >> 5;
  float tr = trans[i*K_ + j];
  int len = lens[b];
  if (tid < K_){
    float a0 = phi[b*K_ + tid] + phi[(size_t)B_*K_ + b*K_ + tid];  // raw0+raw1
    sal[0][tid] = a0; sH[0][tid] = 0.0f;
    alphas[b*K_ + tid] = a0;
  }
  __syncthreads();
  for (int t = 1; t < T_; t++){
    int cur = (t-1) & 1, nxt = t & 1;
    bool active = (t < len);
    float ai = sal[cur][i], Hi = sH[cur][i];
    float aj = sal[cur][j], Hj = sH[cur][j];
    float s = ai + tr;
    float m = s;
    #pragma unroll
    for (int off=16; off; off>>=1) m = fmaxf(m, __shfl_xor(m, off, 32));
    float e = expf(s - m);
    float E = e;
    #pragma unroll
    for (int off=16; off; off>>=1) E += __shfl_xor(E, off, 32);
    float lZ = m + logf(E);
    float w = e / E;
    float logw = s - lZ;
    float nH = w * (Hi - logw);
    #pragma unroll
    for (int off=16; off; off>>=1) nH += __shfl_xor(nH, off, 32);
    float pm = phi[(size_t)(t-1)*B_*K_ + b*K_ + j];
    float pt = phi[(size_t)t*B_*K_ + b*K_ + j];
    float ps = (t == T_-1) ? (pm + 2.0f*pt)
                           : (pm + 2.0f*pt + phi[(size_t)(t+1)*B_*K_ + b*K_ + j]);
    float na = lZ + ps;
    float outa = active ? na : aj;
    float outH = active ? nH : Hj;
    if (i == 0){
      sal[nxt][j] = outa; sH[nxt][j] = outH;
      alphas[(size_t)t*B_*K_ + b*K_ + j] = outa;
    }
    __syncthreads();
  }
  int fb = (T_-1) & 1;
  if (tid < K_){
    float a = sal[fb][tid];
    float m = a;
    #pragma unroll
    for (int off=16; off; off>>=1) m = fmaxf(m, __shfl_xor(m, off, 32));
    float e = expf(a-m), E = e;
    #pragma unroll
    for (int off=16; off; off>>=1) E += __shfl_xor(E, off, 32);
    float lse = m + logf(E);
    float lp = a - lse;
    float v = expf(lp)*(sH[fb][tid]-lp);
    #pragma unroll
    for (int off=16; off; off>>=1) v += __shfl_xor(v, off, 32);
    if (tid == 0) ent_b[b] = v;
  }
}

// ---------------- backward Gumbel sampler
__global__ void k_sampler(const float* __restrict__ alphas, const float* __restrict__ trans,
                          const float* __restrict__ gum, const int* __restrict__ lens,
                          const float* __restrict__ tau_p,
                          float* __restrict__ y_all, int* __restrict__ z_ids){
  int b = blockIdx.x;
  int lane = threadIdx.x;
  int k = lane & 31;
  float inv_tau = d_rcp(tau_p[0]);
  int len = lens[b];
  int nid = 0;
  for (int t = T_-1; t >= 0; t--){
    bool active  = (t < len);
    bool is_last = (t == len-1);
    float a = alphas[(size_t)t*B_*K_ + b*K_ + k];
    float lg = is_last ? a : a + trans[k*K_ + nid];
    float val = (lg + gum[(size_t)t*B_*K_ + b*K_ + k]) * inv_tau;
    float m = val;
    #pragma unroll
    for (int off=16; off; off>>=1) m = fmaxf(m, __shfl_xor(m, off, 32));
    float e = expf(val - m), E = e;
    #pragma unroll
    for (int off=16; off; off>>=1) E += __shfl_xor(E, off, 32);
    float y = active ? e*d_rcp(E) : 0.0f;
    if (lane < K_) y_all[(size_t)(b*T_ + t)*K_ + k] = y;
    float bv = val; int bk = k;
    #pragma unroll
    for (int off=16; off; off>>=1){
      float ov = __shfl_xor(bv, off, 32);
      int   ok = __shfl_xor(bk, off, 32);
      if (ov > bv || (ov == bv && ok < bk)){ bv = ov; bk = ok; }
    }
    int ids = active ? bk : 0;
    nid = ids;
    if (lane == 0) z_ids[b*T_ + t] = ids;
  }
}

// ---------------- attention 1
__global__ __launch_bounds__(256) void k_attn1(
    const float* __restrict__ q, const float* __restrict__ memk,
    const float* __restrict__ kv_emb, const int* __restrict__ keys,
    const float* __restrict__ av, float* __restrict__ ctx){
  __shared__ float se[16];
  int r = blockIdx.x, tid = threadIdx.x;
  int b = r / TD_;
  int m = tid >> 4, ds = tid & 15;
  float p = 0.0f;
  #pragma unroll 4
  for (int qq = 0; qq < 16; qq++){
    int dd = ds + qq*16;
    p += d_tanh(q[(size_t)r*256 + dd] + memk[(size_t)(b*M_+m)*256 + dd]) * av[dd];
  }
  #pragma unroll
  for (int off=8; off; off>>=1) p += __shfl_xor(p, off, 16);
  if (ds == 0) se[m] = (keys[b*M_+m] != 0) ? p : -1e9f;
  __syncthreads();
  float mx = -1e30f;
  #pragma unroll
  for (int mm=0;mm<16;mm++) mx = fmaxf(mx, se[mm]);
  float den = 0.0f, ex[16];
  #pragma unroll
  for (int mm=0;mm<16;mm++){ ex[mm] = __expf(se[mm]-mx); den += ex[mm]; }
  float cacc = 0.0f;
  #pragma unroll
  for (int mm=0;mm<16;mm++) cacc += ex[mm]*kv_emb[(size_t)(b*M_+mm)*256 + tid];
  ctx[(size_t)r*256 + tid] = cacc*d_rcp(den);
}

// ---------------- attention 2 + copy + gate
__global__ __launch_bounds__(256) void k_attn2g(
    const float* __restrict__ q2, const float* __restrict__ dint,
    const float* __restrict__ memk2, const int* __restrict__ keys,
    const float* __restrict__ cv, const float* __restrict__ gW, const float* __restrict__ gb,
    const int* __restrict__ sent,
    float* __restrict__ cpx, float* __restrict__ gsig){
  __shared__ float se2[16];
  __shared__ float sred[4];
  int r = blockIdx.x, tid = threadIdx.x;
  int b = r / TD_, t = r - b*TD_;
  int m = tid >> 4, ds = tid & 15;
  float p = 0.0f;
  #pragma unroll 4
  for (int qq = 0; qq < 16; qq++){
    int dd = ds + qq*16;
    p += d_tanh(q2[(size_t)r*256 + dd] + memk2[(size_t)(b*M_+m)*256 + dd]) * cv[dd];
  }
  #pragma unroll
  for (int off=8; off; off>>=1) p += __shfl_xor(p, off, 16);
  if (ds == 0) se2[m] = (keys[b*M_+m] != 0) ? p : -1e9f;
  float gp = dint[(size_t)r*256 + tid]*gW[tid];
  #pragma unroll
  for (int off=32; off; off>>=1) gp += __shfl_xor(gp, off, 64);
  if ((tid & 63) == 0) sred[tid>>6] = gp;
  __syncthreads();
  if (tid == 0){
    float mx = -1e30f;
    #pragma unroll
    for (int mm=0;mm<16;mm++) mx = fmaxf(mx, se2[mm]);
    float den = 0.0f, ex[16];
    #pragma unroll
    for (int mm=0;mm<16;mm++){ ex[mm] = __expf(se2[mm]-mx); den += ex[mm]; }
    int txi = sent[b*T_ + t + 1];
    float idn = d_rcp(den);
    float cp = 0.0f;
    #pragma unroll
    for (int mm=0;mm<16;mm++) if (keys[b*M_+mm] == txi) cp += ex[mm]*idn;
    cpx[r] = cp;
    gsig[r] = d_sig(sred[0]+sred[1]+sred[2]+sred[3] + gb[0]);
  }
}

// ---------------- dint -> packed fp8 (pack ONCE; bit-identical)
__global__ void k_a8(const float* __restrict__ dint, unsigned* __restrict__ A8){
  int idx = blockIdx.x*256 + threadIdx.x;   // R_*64 u32s
  if (idx >= R_*64) return;
  float4 f = *reinterpret_cast<const float4*>(dint + (size_t)idx*4);
  A8[idx] = pack4_fp8(f.x, f.y, f.z, f.w);
}

// ---------------- fp8 MFMA GEMM + online LSE over V — v3 (r26):
// 128-row A tile (32KB) + double-buffered W (2x16KB) = 64KB total -> keeps
// 2 blocks/CU (r22's dbuf failed only on occupancy at 96KB). ONE barrier per
// chunk; W loads issued 2 chunks ahead so L2 latency hides under MFMA.
// grid.x = R_/128 = 127. Per-lane online (m,s); part[] semantics unchanged.
__global__ __launch_bounds__(512) void k_lse8(
    const unsigned char* __restrict__ A8,   // dint fp8 [R][256] bytes
    const unsigned char* __restrict__ Wt8,  // [V][256] fp8
    const float* __restrict__ bias,
    float* __restrict__ part){              // [R][NCH_][2]
  __shared__ unsigned char Al[128*256];     // 32KB, swizzled fp8
  __shared__ unsigned char Wl[2][64*256];   // 32KB, double-buffered
  int tid = threadIdx.x;
  int row0 = blockIdx.x*128;
  // stage A: 128 rows x 256B via 4x uint4/thread
  #pragma unroll
  for (int q = 0; q < 4; q++){
    int u = tid + q*512;
    int row = u >> 4, s16a = u & 15;
    int r = row0 + row;
    uint4 pk = (uint4){0u,0u,0u,0u};
    if (r < R_)
      pk = *reinterpret_cast<const uint4*>(A8 + (size_t)r*256 + s16a*16);
    int dst = row*256 + ((s16a*16) ^ ((row&7)<<4));
    *reinterpret_cast<uint4*>(&Al[dst]) = pk;
  }
  // W staging geometry (chunk-invariant)
  int s16 = tid & 15;
  int c0q = tid >> 4;            // 0..31
  int c1q = c0q + 32;
  int src0 = c0q*256 + s16*16;
  int src1 = c1q*256 + s16*16;
  int dst0 = c0q*256 + ((s16*16) ^ ((c0q&7)<<4));
  int dst1 = c1q*256 + ((s16*16) ^ ((c1q&7)<<4));
  uint4 wr0, wr1;
  int ct0 = blockIdx.y;
  // prologue: chunk0 -> Wl[0]; chunk1 held in regs
  wr0 = *reinterpret_cast<const uint4*>(Wt8 + (size_t)ct0*16384 + src0);
  wr1 = *reinterpret_cast<const uint4*>(Wt8 + (size_t)ct0*16384 + src1);
  *reinterpret_cast<uint4*>(&Wl[0][dst0]) = wr0;
  *reinterpret_cast<uint4*>(&Wl[0][dst1]) = wr1;
  if (ct0 + NCH_ < 500){
    wr0 = *reinterpret_cast<const uint4*>(Wt8 + (size_t)(ct0+NCH_)*16384 + src0);
    wr1 = *reinterpret_cast<const uint4*>(Wt8 + (size_t)(ct0+NCH_)*16384 + src1);
  }
  __syncthreads();   // A + Wl[0] staged

  int w = tid >> 6, l = tid & 63;
  int arow = 16*w + (l & 15);              // 0..127 (8 waves)
  long long afr[8];
  #pragma unroll
  for (int k0 = 0; k0 < 8; k0++){
    int kb = k0*32 + ((l>>4)*8);
    afr[k0] = *reinterpret_cast<const long long*>(&Al[arow*256 + (kb ^ ((arow&7)<<4))]);
  }
  float rm[4], rs[4];                      // per-lane over its 4-col slice
  #pragma unroll
  for (int r4=0;r4<4;r4++){ rm[r4] = -3.0e38f; rs[r4] = 0.0f; }

  int it = 0;
  for (int ct = ct0; ct < 500; ct += NCH_, it++){
    int cur = it & 1, nxt = cur ^ 1;
    // write the held next-chunk regs into the other buffer
    if (ct + NCH_ < 500){
      *reinterpret_cast<uint4*>(&Wl[nxt][dst0]) = wr0;
      *reinterpret_cast<uint4*>(&Wl[nxt][dst1]) = wr1;
    }
    // issue loads for chunk+2 (retire under MFMA)
    if (ct + 2*NCH_ < 500){
      wr0 = *reinterpret_cast<const uint4*>(Wt8 + (size_t)(ct+2*NCH_)*16384 + src0);
      wr1 = *reinterpret_cast<const uint4*>(Wt8 + (size_t)(ct+2*NCH_)*16384 + src1);
    }
    const unsigned char* Wc = Wl[cur];
    f32x4 acc[4];
    #pragma unroll
    for (int nf=0;nf<4;nf++) acc[nf] = (f32x4){0.f,0.f,0.f,0.f};
    #pragma unroll
    for (int k0 = 0; k0 < 8; k0++){
      int kb = k0*32 + ((l>>4)*8);
      #pragma unroll
      for (int nf = 0; nf < 4; nf++){
        int bc = nf*16 + (l & 15);
        long long bfr = *reinterpret_cast<const long long*>(&Wc[bc*256 + (kb ^ ((bc&7)<<4))]);
        acc[nf] = __builtin_amdgcn_mfma_f32_16x16x32_fp8_fp8(afr[k0], bfr, acc[nf], 0, 0, 0);
      }
    }
    int col0 = ct*64;
    float bb[4];
    #pragma unroll
    for (int nf=0;nf<4;nf++) bb[nf] = bias[col0 + nf*16 + (l&15)];
    #pragma unroll
    for (int r4 = 0; r4 < 4; r4++){
      float v0 = acc[0][r4]+bb[0], v1 = acc[1][r4]+bb[1];
      float v2 = acc[2][r4]+bb[2], v3 = acc[3][r4]+bb[3];
      float tm = fmaxf(fmaxf(v0,v1), fmaxf(v2,v3));
      float ts = __expf(v0-tm)+__expf(v1-tm)+__expf(v2-tm)+__expf(v3-tm);
      float m0 = rm[r4];
      if (tm <= m0){
        rs[r4] += ts*__expf(tm - m0);
      } else {
        rs[r4] = rs[r4]*__expf(m0 - tm) + ts;
        rm[r4] = tm;
      }
    }
    __syncthreads();   // reads of Wl[cur] done before it is rewritten
  }
  // one-time 16-lane row-group combine (same part[] semantics)
  #pragma unroll
  for (int r4 = 0; r4 < 4; r4++){
    float M = rm[r4];
    #pragma unroll
    for (int off=8; off; off>>=1) M = fmaxf(M, __shfl_xor(M, off, 16));
    float S = rs[r4]*__expf(rm[r4] - M);
    #pragma unroll
    for (int off=8; off; off>>=1) S += __shfl_xor(S, off, 16);
    if ((l & 15) == 0){
      int grow = row0 + 16*w + (l>>4)*4 + r4;
      if (grow < R_){
        part[((size_t)grow*NCH_ + blockIdx.y)*2 + 0] = M;
        part[((size_t)grow*NCH_ + blockIdx.y)*2 + 1] = S;
      }
    }
  }
}

__global__ void k_lse_combine(const float* __restrict__ part, float* __restrict__ lse){
  int r = blockIdx.x*256 + threadIdx.x;
  if (r >= R_) return;
  float M = -3.0e38f;
  for (int c = 0; c < NCH_; c++) M = fmaxf(M, part[((size_t)r*NCH_+c)*2]);
  float S = 0.0f;
  for (int c = 0; c < NCH_; c++){
    float m = part[((size_t)r*NCH_+c)*2], s = part[((size_t)r*NCH_+c)*2+1];
    S += s*__expf(m - M);
  }
  lse[r] = M + logf(S);
}

// target logit from the SAME quantized weights/activations as the LSE
__global__ __launch_bounds__(256) void k_ltx(const unsigned char* __restrict__ A8,
    const unsigned char* __restrict__ Wt8, const float* __restrict__ bias,
    const int* __restrict__ sent, float* __restrict__ out){
  int tid = threadIdx.x;
  int r = blockIdx.x*4 + (tid >> 6);
  int lane = tid & 63;
  int b = r / TD_, t = r - b*TD_;
  int tx = sent[b*T_ + t + 1];
  unsigned wq = *reinterpret_cast<const unsigned*>(Wt8 + (size_t)tx*256 + lane*4);
  float wv[4]; cvt4_fp8(wq, wv);
  unsigned aq = *reinterpret_cast<const unsigned*>(A8 + (size_t)r*256 + lane*4);
  float av[4]; cvt4_fp8(aq, av);
  float acc = av[0]*wv[0] + av[1]*wv[1] + av[2]*wv[2] + av[3]*wv[3];
  #pragma unroll
  for (int off=32; off; off>>=1) acc += __shfl_xor(acc, off, 64);
  if (lane == 0) out[r] = acc + bias[tx];
}

__global__ __launch_bounds__(256) void k_final(
    const float* __restrict__ lse, const float* __restrict__ ltx,
    const float* __restrict__ gsig, const float* __restrict__ cpx,
    const float* __restrict__ lpz, const float* __restrict__ ent_b,
    const int* __restrict__ lens, float* __restrict__ out){
  __shared__ float sred[256];
  int tid = threadIdx.x;
  float sum = 0.0f;
  for (int r = tid; r < R_; r += 256){
    int b = r / TD_, t = r % TD_;
    if (t < lens[b]){
      float g = gsig[r];
      float lm = __expf(ltx[r] - lse[r]);
      float p = (1.0f-g)*lm + g*cpx[r] + 1e-10f;
      sum += logf(p) + lpz[r];
    }
  }
  sred[tid] = sum;
  __syncthreads();
  for (int s = 128; s; s >>= 1){ if (tid < s) sred[tid] += sred[tid+s]; __syncthreads(); }
  if (tid == 0){
    float es = 0.0f, dn = 0.0f;
    for (int b = 0; b < B_; b++){ es += ent_b[b]; dn += (float)lens[b]; }
    out[0] = -( es/(float)B_ + sred[0]/dn );
  }
}

} // anonymous namespace

extern "C" void kernel_launch(void* const* d_in, const int* in_sizes, int n_in,
                              void* d_out, int out_size, void* d_ws, size_t ws_size,
                              hipStream_t stream){
  const int*   keys  = (const int*)d_in[0];
  const int*   vals  = (const int*)d_in[1];
  const int*   sent  = (const int*)d_in[2];
  const int*   lens  = (const int*)d_in[3];
  const float* tau   = (const float*)d_in[4];
  const float* xl    = (const float*)d_in[5];
  const float* gum   = (const float*)d_in[6];
  const float* drop  = (const float*)d_in[7];
  const float* emb   = (const float*)d_in[8];
  const float* z_emb = (const float*)d_in[9];
  const float* eWih  = (const float*)d_in[10];
  const float* eWhh  = (const float*)d_in[11];
  const float* eb    = (const float*)d_in[12];
  const float* crfW  = (const float*)d_in[13];
  const float* crfb  = (const float*)d_in[14];
  const float* trans = (const float*)d_in[15];
  const float* iWh   = (const float*)d_in[16];
  const float* ibh   = (const float*)d_in[17];
  const float* iWc   = (const float*)d_in[18];
  const float* ibc   = (const float*)d_in[19];
  const float* dWih  = (const float*)d_in[20];
  const float* dWhh  = (const float*)d_in[21];
  const float* db    = (const float*)d_in[22];
  const float* aWq   = (const float*)d_in[23];
  const float* aWk   = (const float*)d_in[24];
  const float* av    = (const float*)d_in[25];
  const float* aoW   = (const float*)d_in[26];
  const float* aob   = (const float*)d_in[27];
  const float* pzW   = (const float*)d_in[28];
  const float* pzb   = (const float*)d_in[29];
  const float* intW  = (const float*)d_in[30];
  const float* intb  = (const float*)d_in[31];
  const float* outW  = (const float*)d_in[32];
  const float* outb  = (const float*)d_in[33];
  const float* cWq   = (const float*)d_in[34];
  const float* cWk   = (const float*)d_in[35];
  const float* cv    = (const float*)d_in[36];
  const float* gW    = (const float*)d_in[37];
  const float* gb    = (const float*)d_in[38];
  (void)in_sizes; (void)n_in; (void)out_size; (void)ws_size;

  float* ws = (float*)d_ws;
  size_t o = 0;
  auto alloc = [&](size_t n){ size_t r = o; o += (n + 3) & ~(size_t)3; return r; };
  float* sent_emb = ws + alloc((size_t)B_*T_*D_);
  float* kv_emb   = ws + alloc((size_t)B_*M_*D_);
  float* kv_enc   = ws + alloc((size_t)B_*D_);
  float* h0       = ws + alloc((size_t)B_*D_);
  float* c0       = ws + alloc((size_t)B_*D_);
  float* memk     = ws + alloc((size_t)B_*M_*D_);
  float* memk2    = ws + alloc((size_t)B_*M_*D_);
  float* xW       = ws + alloc((size_t)B_*T_*D4_);
  float* encH     = ws + alloc((size_t)B_*T_*D_);
  float* phi_raw  = ws + alloc((size_t)T_*B_*K_);
  float* alphas   = ws + alloc((size_t)T_*B_*K_);
  float* ent_b    = ws + alloc((size_t)B_);
  float* y_all    = ws + alloc((size_t)B_*T_*K_);
  float* zse      = ws + alloc((size_t)B_*T_*D_);
  float* qbuf     = ws + alloc((size_t)R_*D_);
  float* ctx      = ws + alloc((size_t)R_*D_);
  float* dec_out  = ws + alloc((size_t)R_*D_);
  float* dint     = ws + alloc((size_t)R_*D_);
  float* lpz_b    = ws + alloc((size_t)R_);
  float* gsig     = ws + alloc((size_t)R_);
  float* cpx      = ws + alloc((size_t)R_);
  float* ltx      = ws + alloc((size_t)R_);
  float* lse      = ws + alloc((size_t)R_);
  float* part     = ws + alloc((size_t)R_*NCH_*2);
  int*   z_ids    = (int*)(ws + alloc((size_t)B_*T_));
  unsigned* A8    = (unsigned*)(ws + alloc((size_t)R_*64));
  unsigned char* WhhT8E = (unsigned char*)(ws + alloc((size_t)D4_*D_/4));
  unsigned char* WhhT8D = (unsigned char*)(ws + alloc((size_t)D4_*D_/4));
  unsigned char* Wt8    = (unsigned char*)(ws + alloc((size_t)V_*D_/4));
  unsigned short* eWihT = (unsigned short*)(ws + alloc((size_t)D4_*D_/2));
  unsigned short* dWihT = (unsigned short*)(ws + alloc((size_t)D4_*D_/2));
  unsigned short* aWqT  = (unsigned short*)(ws + alloc((size_t)D_*D_/2));
  unsigned short* cWqT  = (unsigned short*)(ws + alloc((size_t)D_*D_/2));
  unsigned short* aoWtT = (unsigned short*)(ws + alloc((size_t)D_*D_/2));
  unsigned short* aoWbT = (unsigned short*)(ws + alloc((size_t)D_*D_/2));
  unsigned short* inWtT = (unsigned short*)(ws + alloc((size_t)D_*D_/2));
  unsigned short* inWbT = (unsigned short*)(ws + alloc((size_t)D_*D_/2));

  float* Hdec = encH;   // alias: enc_out dead after k_phi

  // prep (fused launches)
  k_emb2<<<B_*T_ + B_*M_, 256, 0, stream>>>(sent, keys, vals, emb, sent_emb, kv_emb);
  k_kv_enc<<<B_*D_/256, 256, 0, stream>>>(keys, kv_emb, kv_enc);
  k_rowgemm2<<<B_, 256, 0, stream>>>(kv_enc, iWh, ibh, h0, iWc, ibc, c0, 256, 256);
  k_rowgemm2<<<B_*M_, 256, 0, stream>>>(kv_emb, aWk, nullptr, memk,
                                        cWk, nullptr, memk2, 256, 256);
  k_wt8_2<<<32, 256, 0, stream>>>(eWhh, dWhh, WhhT8E, WhhT8D, D4_);
  k_wt8<<<V_/64, 256, 0, stream>>>(outW, Wt8, V_);
  k_wtg2<<<32, 256, 0, stream>>>(eWih, dWih, eWihT, dWihT, D4_);
  k_wtg6<<<24, 256, 0, stream>>>(aWq, cWq, aoW, aoW + 256*256, intW, intW + 256*256,
                                 aWqT, cWqT, aoWtT, aoWbT, inWtT, inWbT);

  // encoder (xW written time-major [t][B][1024] via TMD=T_)
  k_gemm<0,0,1,4,true,T_><<<dim3(B_*T_/128, 4), 512, 0, stream>>>(
      sent_emb, nullptr, eWihT, nullptr, eb, xW, D4_, nullptr, nullptr);
  k_lstm12<<<B_/16, 1024, 0, stream>>>(xW, WhhT8E, nullptr, nullptr, encH, T_);
  k_phi<<<B_*T_/8, 256, 0, stream>>>(encH, crfW, crfb, phi_raw);
  k_crf<<<B_, 1024, 0, stream>>>(phi_raw, trans, lens, alphas, ent_b);
  k_sampler<<<B_, 64, 0, stream>>>(alphas, trans, gum, lens, tau, y_all, z_ids);
  k_rowgemm<<<B_*T_, 256, 0, stream>>>(y_all, z_emb, nullptr, zse, K_, 256);

  // decoder inputs (time-major via TMD=TD_) + scan
  k_gemm<1,0,1,4,true,TD_><<<dim3(R_/128, 4), 512, 0, stream>>>(
      sent_emb, zse, dWihT, nullptr, db, xW, D4_, drop, xl);
  k_lstm12<<<B_/16, 1024, 0, stream>>>(xW, WhhT8D, h0, c0, Hdec, TD_);

  // decoder post-processing (parallel over R rows)
  k_gemm<0,0,1,1,false,0><<<dim3(R_/128, 4), 512, 0, stream>>>(
      Hdec, nullptr, aWqT, nullptr, nullptr, qbuf, D_, nullptr, nullptr);
  k_attn1<<<R_, 256, 0, stream>>>(qbuf, memk, kv_emb, keys, av, ctx);
  k_gemm<0,0,2,1,true,0><<<dim3(R_/128, 4), 512, 0, stream>>>(
      Hdec, ctx, aoWtT, aoWbT, aob, dec_out, D_, nullptr, nullptr);
  k_zlp<<<R_/8, 256, 0, stream>>>(dec_out, pzW, pzb, z_ids, lpz_b);
  k_gemm<0,2,2,1,true,0><<<dim3(R_/128, 4), 512, 0, stream>>>(
      dec_out, zse, inWtT, inWbT, intb, dint, D_, nullptr, nullptr);
  k_a8<<<(R_*64+255)/256, 256, 0, stream>>>(dint, A8);
  k_gemm<0,0,1,1,false,0><<<dim3(R_/128, 4), 512, 0, stream>>>(
      dint, nullptr, cWqT, nullptr, nullptr, qbuf, D_, nullptr, nullptr);
  k_attn2g<<<R_, 256, 0, stream>>>(qbuf, dint, memk2, keys, cv, gW, gb, sent,
                                   cpx, gsig);

  // vocab LSE (fp8 MFMA) + target logit + loss
  k_lse8<<<dim3(R_/128, NCH_), 512, 0, stream>>>(
      (const unsigned char*)A8, Wt8, outb, part);
  k_lse_combine<<<(R_+255)/256, 256, 0, stream>>>(part, lse);
  k_ltx<<<R_/4, 256, 0, stream>>>((const unsigned char*)A8, Wt8, outb, sent, ltx);
  k_final<<<1, 256, 0, stream>>>(lse, ltx, gsig, cpx, lpz_b, ent_b, lens, (float*)d_out);
}

// Round 27
// 1708.169 us; speedup vs baseline: 1.0551x; 1.0551x over previous
//
#include <hip/hip_runtime.h>
#include <math.h>

namespace {

constexpr int V_  = 32000;
constexpr int K_  = 32;
constexpr int D_  = 256;
constexpr int T_  = 128;
constexpr int B_  = 128;
constexpr int M_  = 16;
constexpr int D4_ = 1024;
constexpr int TD_ = T_ - 1;      // 127
constexpr int R_  = B_ * TD_;    // 16256
constexpr int NCH_ = 8;          // lse grid-y chunks

typedef __attribute__((ext_vector_type(8))) short short8;
typedef __attribute__((ext_vector_type(4))) float f32x4;
typedef __attribute__((ext_vector_type(2))) float f32x2;

// fast reciprocal (v_rcp_f32, ~1ulp; rcp(inf)=0 keeps sig/tanh saturation exact)
__device__ __forceinline__ float d_rcp(float x){
#if __has_builtin(__builtin_amdgcn_rcpf)
  return __builtin_amdgcn_rcpf(x);
#else
  return 1.0f / x;
#endif
}
__device__ __forceinline__ float d_sig(float x){
  return d_rcp(1.0f + __expf(-x));
}
__device__ __forceinline__ float d_tanh(float x){
  float e = __expf(2.0f*x);          // inf-safe: rcp(inf)=0 -> tanh=1
  return 1.0f - 2.0f*d_rcp(e + 1.0f);
}
__device__ __forceinline__ unsigned short f2bf(float f){  // RNE fp32->bf16
  unsigned int x = __float_as_uint(f);
  unsigned int r = (x + 0x7FFFu + ((x>>16)&1u)) >> 16;
  return (unsigned short)r;
}

// fp32 -> OCP e4m3 (RNE, denormal-correct; clamps at 448)  [software path]
__device__ __forceinline__ unsigned f2fp8(float f){
  unsigned u = __float_as_uint(f);
  unsigned s = (u>>31)<<7;
  float a = fabsf(f);
  if (a < 0.015625f){
    int m = (int)rintf(a*512.0f);
    if (m >= 8) return s | 0x08u;
    return s | (unsigned)m;
  }
  unsigned t = u & 0x7FFFFFFFu;
  t += 0x7FFFFu + ((t>>20)&1u);
  int E = (int)(t>>23) - 127 + 7;
  if (E >= 16) return s | 0x7Eu;
  return s | ((unsigned)E<<3) | ((t>>20)&7u);
}

// pack 4 floats -> 4x fp8 (HW v_cvt_pk_fp8_f32 on gfx950; sw fallback identical)
__device__ __forceinline__ unsigned pack4_fp8(float a, float b, float c, float d){
#if __has_builtin(__builtin_amdgcn_cvt_pk_fp8_f32)
  unsigned r = (unsigned)__builtin_amdgcn_cvt_pk_fp8_f32(a, b, 0, false);
  r = (unsigned)__builtin_amdgcn_cvt_pk_fp8_f32(c, d, (int)r, true);
  return r;
#else
  return f2fp8(a) | (f2fp8(b)<<8) | (f2fp8(c)<<16) | (f2fp8(d)<<24);
#endif
}
__device__ __forceinline__ unsigned char f2fp8_b(float f){  // single byte, HW path
#if __has_builtin(__builtin_amdgcn_cvt_pk_fp8_f32)
  return (unsigned char)(__builtin_amdgcn_cvt_pk_fp8_f32(f, f, 0, false) & 0xFF);
#else
  return (unsigned char)f2fp8(f);
#endif
}

// 4x fp8 (packed u32) -> 4x f32  [validated r8/r10: absmax 0.0]
__device__ __forceinline__ void cvt4_fp8(unsigned w, float* o){
#if __has_builtin(__builtin_amdgcn_cvt_pk_f32_fp8)
  f32x2 lo = __builtin_amdgcn_cvt_pk_f32_fp8(w, false);
  f32x2 hi = __builtin_amdgcn_cvt_pk_f32_fp8(w, true);
  o[0]=lo.x; o[1]=lo.y; o[2]=hi.x; o[3]=hi.y;
#else
  #pragma unroll
  for (int j = 0; j < 4; j++){
    unsigned b = (w>>(8*j)) & 0xFFu;
    unsigned e = (b>>3) & 15u, m = b & 7u;
    float mag = e ? __uint_as_float(((e+120u)<<23)|(m<<20)) : (float)m*0.001953125f;
    o[j] = (b & 0x80u) ? -mag : mag;
  }
#endif
}

// ---------------- prep ----------------
// fused sent_emb + kv_emb: blocks [0,B*T) sent rows, rest kv rows
__global__ void k_emb2(const int* __restrict__ sent, const int* __restrict__ keys,
                       const int* __restrict__ vals, const float* __restrict__ emb,
                       float* __restrict__ sent_emb, float* __restrict__ kv){
  int bid = blockIdx.x, tid = threadIdx.x;
  if (bid < B_*T_){
    sent_emb[(size_t)bid*256 + tid] = emb[(size_t)sent[bid]*D_ + tid];
  } else {
    int r = bid - B_*T_;
    kv[(size_t)r*256 + tid] = emb[(size_t)keys[r]*D_ + tid]
                            + emb[(size_t)vals[r]*D_ + tid];
  }
}

__global__ void k_kv_enc(const int* __restrict__ keys, const float* __restrict__ kv,
                         float* __restrict__ out){
  int idx = blockIdx.x*256 + threadIdx.x;     // B*D
  int b = idx >> 8, d = idx & 255;
  float s = 0.0f, c = 0.0f;
  for (int m = 0; m < M_; m++){
    if (keys[b*M_+m] != 0){ s += kv[(size_t)(b*M_+m)*D_ + d]; c += 1.0f; }
  }
  out[idx] = s / c;
}

// one block per row: C[r][j] = sum_d A[r][d]*W[d][j] + bias
__global__ void k_rowgemm(const float* __restrict__ A, const float* __restrict__ W,
                          const float* __restrict__ bias, float* __restrict__ C,
                          int inner, int cols){
  __shared__ float sA[256];
  int r = blockIdx.x;
  if ((int)threadIdx.x < inner) sA[threadIdx.x] = A[(size_t)r*inner + threadIdx.x];
  __syncthreads();
  for (int j = threadIdx.x; j < cols; j += blockDim.x){
    float acc = bias ? bias[j] : 0.0f;
    #pragma unroll 4
    for (int d = 0; d < inner; d++) acc += sA[d]*W[(size_t)d*cols + j];
    C[(size_t)r*cols + j] = acc;
  }
}

// two outputs from one staged A row (h0/c0, memk/memk2)
__global__ void k_rowgemm2(const float* __restrict__ A,
                           const float* __restrict__ W1, const float* __restrict__ b1,
                           float* __restrict__ C1,
                           const float* __restrict__ W2, const float* __restrict__ b2,
                           float* __restrict__ C2, int inner, int cols){
  __shared__ float sA[256];
  int r = blockIdx.x;
  if ((int)threadIdx.x < inner) sA[threadIdx.x] = A[(size_t)r*inner + threadIdx.x];
  __syncthreads();
  for (int j = threadIdx.x; j < cols; j += blockDim.x){
    float a1 = b1 ? b1[j] : 0.0f;
    float a2 = b2 ? b2[j] : 0.0f;
    #pragma unroll 4
    for (int d = 0; d < inner; d++){
      float a = sA[d];
      a1 += a*W1[(size_t)d*cols + j];
      a2 += a*W2[(size_t)d*cols + j];
    }
    C1[(size_t)r*cols + j] = a1;
    C2[(size_t)r*cols + j] = a2;
  }
}

// ---------------- transpose + fp8: W[256][ldw-span] -> Wt8[cols][256] bytes
__global__ __launch_bounds__(256) void k_wt8(const float* __restrict__ W,
                                             unsigned char* __restrict__ Wt8, int ldw){
  __shared__ unsigned char st[64][272];
  int tid = threadIdx.x; size_t c0 = (size_t)blockIdx.x*64;
  for (int l = tid; l < 64*256; l += 256){
    int k = l >> 6, c = l & 63;
    st[c][k] = f2fp8_b(W[(size_t)k*ldw + c0 + c]);
  }
  __syncthreads();
  for (int l = tid; l < 64*16; l += 256){
    int c = l >> 4, s = l & 15;
    *reinterpret_cast<uint4*>(&Wt8[(c0+c)*256 + s*16]) =
      *reinterpret_cast<const uint4*>(&st[c][s*16]);
  }
}

// two Whh transposes in one launch (32 blocks)
__global__ __launch_bounds__(256) void k_wt8_2(const float* __restrict__ W1,
    const float* __restrict__ W2, unsigned char* __restrict__ O1,
    unsigned char* __restrict__ O2, int ldw){
  __shared__ unsigned char st[64][272];
  const float* W = (blockIdx.x < 16) ? W1 : W2;
  unsigned char* O = (blockIdx.x < 16) ? O1 : O2;
  int tid = threadIdx.x; size_t c0 = (size_t)(blockIdx.x & 15)*64;
  for (int l = tid; l < 64*256; l += 256){
    int k = l >> 6, c = l & 63;
    st[c][k] = f2fp8_b(W[(size_t)k*ldw + c0 + c]);
  }
  __syncthreads();
  for (int l = tid; l < 64*16; l += 256){
    int c = l >> 4, s = l & 15;
    *reinterpret_cast<uint4*>(&O[(c0+c)*256 + s*16]) =
      *reinterpret_cast<const uint4*>(&st[c][s*16]);
  }
}

// two bf16 1024-col transposes in one launch (32 blocks)
__global__ __launch_bounds__(256) void k_wtg2(const float* __restrict__ W1,
    const float* __restrict__ W2, unsigned short* __restrict__ O1,
    unsigned short* __restrict__ O2, int ldw){
  __shared__ unsigned short st[64][264];
  const float* W = (blockIdx.x < 16) ? W1 : W2;
  unsigned short* O = (blockIdx.x < 16) ? O1 : O2;
  int tid = threadIdx.x; size_t c0 = (size_t)(blockIdx.x & 15)*64;
  for (int l = tid; l < 64*256; l += 256){
    int k = l >> 6, c = l & 63;
    st[c][k] = f2bf(W[(size_t)k*ldw + c0 + c]);
  }
  __syncthreads();
  for (int l = tid; l < 64*32; l += 256){
    int c = l >> 5, s = l & 31;
    *reinterpret_cast<uint4*>(&O[(c0+c)*256 + s*8]) =
      *reinterpret_cast<const uint4*>(&st[c][s*8]);
  }
}

// six 256x256 transposes in one launch (24 blocks)
__global__ __launch_bounds__(256) void k_wtg6(
    const float* s0, const float* s1, const float* s2,
    const float* s3, const float* s4, const float* s5,
    unsigned short* d0, unsigned short* d1, unsigned short* d2,
    unsigned short* d3, unsigned short* d4, unsigned short* d5){
  __shared__ unsigned short st[64][264];
  int m = blockIdx.x >> 2, blk = blockIdx.x & 3;
  const float* S; unsigned short* D;
  if      (m == 0){ S = s0; D = d0; }
  else if (m == 1){ S = s1; D = d1; }
  else if (m == 2){ S = s2; D = d2; }
  else if (m == 3){ S = s3; D = d3; }
  else if (m == 4){ S = s4; D = d4; }
  else            { S = s5; D = d5; }
  int tid = threadIdx.x; size_t c0 = (size_t)blk*64;
  for (int l = tid; l < 64*256; l += 256){
    int k = l >> 6, c = l & 63;
    st[c][k] = f2bf(S[(size_t)k*256 + c0 + c]);
  }
  __syncthreads();
  for (int l = tid; l < 64*32; l += 256){
    int c = l >> 5, s = l & 31;
    *reinterpret_cast<uint4*>(&D[(c0+c)*256 + s*8]) =
      *reinterpret_cast<const uint4*>(&st[c][s*8]);
  }
}

// ---------------- generic bf16-MFMA GEMM (passing since r3)
// TMD: 0 = row-major C; else C row permuted r=b*TMD+t -> (t*B_+b) (time-major
// scan input; TMD = T_ for encoder rows b*128+t, TD_ for decoder rows b*127+t)
template<int G1, int G2, int HALVES, int CPB, bool BIAS, int TMD>
__global__ __launch_bounds__(512) void k_gemm(
    const float* __restrict__ A1, const float* __restrict__ A2,
    const unsigned short* __restrict__ W1, const unsigned short* __restrict__ W2,
    const float* __restrict__ bias, float* __restrict__ C, int cols,
    const float* __restrict__ drop, const float* __restrict__ xl){
  __shared__ unsigned short Al[128*256];
  __shared__ unsigned short Wl[64*256];
  int tid = threadIdx.x;
  int row0 = blockIdx.x*128;
  int w = tid >> 6, l = tid & 63;
  int arow = 16*w + (l & 15);
  float xlv = 0.0f;
  if constexpr (G1==1) xlv = xl[0];
  f32x4 acc[CPB][4];
  #pragma unroll
  for (int cc=0;cc<CPB;cc++)
    #pragma unroll
    for (int nf=0;nf<4;nf++) acc[cc][nf] = (f32x4){0.f,0.f,0.f,0.f};

  for (int h = 0; h < HALVES; h++){
    const float* Asrc = h ? A2 : A1;
    const unsigned short* Wt = h ? W2 : W1;
    int gm = h ? G2 : G1;
    __syncthreads();
    #pragma unroll
    for (int q = 0; q < 8; q++){
      int u = tid + q*512;
      int row = u >> 5, slot = u & 31;
      int r = row0 + row;
      float vals[8];
      if (gm == 0){
        const float* s = Asrc + (size_t)r*256 + slot*8;
        #pragma unroll
        for (int j=0;j<8;j++) vals[j] = s[j];
      } else if (gm == 1){
        int b = r / TD_, t = r - b*TD_;
        int bt = b*T_ + t;
        float wm = (drop[bt] > xlv) ? 1.0f : 0.0f;
        const float* se = A1 + (size_t)bt*256 + slot*8;
        const float* zs = A2 + (size_t)bt*256 + slot*8;
        #pragma unroll
        for (int j=0;j<8;j++) vals[j] = se[j]*wm + (t>0 ? zs[j] : 0.0f);
      } else {
        int b = r / TD_, t = r - b*TD_;
        const float* s = Asrc + (size_t)(b*T_ + t + 1)*256 + slot*8;
        #pragma unroll
        for (int j=0;j<8;j++) vals[j] = s[j];
      }
      union { unsigned short us[8]; uint4 v4; } tu;
      #pragma unroll
      for (int j=0;j<8;j++) tu.us[j] = f2bf(vals[j]);
      int dst = row*512 + ((slot*16) ^ ((row&7)<<4));
      *reinterpret_cast<uint4*>(reinterpret_cast<char*>(Al) + dst) = tu.v4;
    }
    __syncthreads();
    short8 afr[8];
    #pragma unroll
    for (int k0 = 0; k0 < 8; k0++){
      int kb = k0*64 + ((l>>4)*16);
      afr[k0] = *reinterpret_cast<const short8*>(
          reinterpret_cast<const char*>(Al) + arow*512 + (kb ^ ((arow&7)<<4)));
    }
    for (int cc = 0; cc < CPB; cc++){
      int col0 = (blockIdx.y*CPB + cc)*64;
      __syncthreads();
      #pragma unroll
      for (int q = 0; q < 4; q++){
        int u = tid + q*512;
        int c = u >> 5, slot = u & 31;
        int dst = c*512 + ((slot*16) ^ ((c&7)<<4));
        *reinterpret_cast<uint4*>(reinterpret_cast<char*>(Wl) + dst) =
          *reinterpret_cast<const uint4*>(
              reinterpret_cast<const char*>(Wt) + (size_t)(col0+c)*512 + slot*16);
      }
      __syncthreads();
      #pragma unroll
      for (int k0 = 0; k0 < 8; k0++){
        int kb = k0*64 + ((l>>4)*16);
        #pragma unroll
        for (int nf = 0; nf < 4; nf++){
          int bc = nf*16 + (l & 15);
          short8 bfr = *reinterpret_cast<const short8*>(
              reinterpret_cast<const char*>(Wl) + bc*512 + (kb ^ ((bc&7)<<4)));
          acc[cc][nf] = __builtin_amdgcn_mfma_f32_16x16x32_bf16(afr[k0], bfr, acc[cc][nf], 0, 0, 0);
        }
      }
    }
  }
  #pragma unroll
  for (int cc = 0; cc < CPB; cc++){
    int col0 = (blockIdx.y*CPB + cc)*64;
    #pragma unroll
    for (int nf = 0; nf < 4; nf++){
      int col = col0 + nf*16 + (l & 15);
      float bv = BIAS ? bias[col] : 0.0f;
      #pragma unroll
      for (int r4 = 0; r4 < 4; r4++){
        int row = row0 + 16*w + (l>>4)*4 + r4;
        size_t orow;
        if constexpr (TMD == 0){
          orow = (size_t)row;
        } else {
          int bb = row / TMD, tt = row - bb*TMD;
          orow = (size_t)tt*B_ + bb;
        }
        C[orow*cols + col] = acc[cc][nf][r4] + bv;
      }
    }
  }
}

// ---------------- LSTM scan v16 (r23/r25-EXACT, proven 328us)
__global__ __launch_bounds__(1024, 4) void k_lstm12(
    const float* __restrict__ xW,          // [NT][B][1024] time-major
    const unsigned char* __restrict__ Wt,  // WhhT8 [1024][256] fp8
    const float* __restrict__ h0, const float* __restrict__ c0,
    float* __restrict__ Hout,              // [B][NT][256]
    int NT){
  __shared__ unsigned char Wl[512*256];    // cols 0..511 (gates i,f), swizzled
  __shared__ unsigned char Ahl[2][16*256]; // h fp8, double buffer (8KB)
  int g0 = blockIdx.x;                     // batches 16g0..16g0+15
  int tid = threadIdx.x;
  int w = tid >> 6, l = tid & 63;          // wave 0..15, lane

  // stage Wl (cols 0..511) with the k_lse8 swizzle
  for (int i = tid; i < 512*16; i += 1024){
    int c = i >> 4, s16 = i & 15;
    int dst = c*256 + ((s16*16) ^ ((c&7)<<4));
    *reinterpret_cast<uint4*>(&Wl[dst]) =
      *reinterpret_cast<const uint4*>(&Wt[(size_t)c*256 + s16*16]);
  }
  // stage initial h fp8 into Ahl[0]
  if (tid < 256){
    int row = tid >> 4, gblk = tid & 15;
    unsigned pk[4];
    #pragma unroll
    for (int g = 0; g < 4; g++){
      float v0 = h0 ? h0[(size_t)(g0*16+row)*256 + gblk*16 + 4*g + 0] : 0.0f;
      float v1 = h0 ? h0[(size_t)(g0*16+row)*256 + gblk*16 + 4*g + 1] : 0.0f;
      float v2 = h0 ? h0[(size_t)(g0*16+row)*256 + gblk*16 + 4*g + 2] : 0.0f;
      float v3 = h0 ? h0[(size_t)(g0*16+row)*256 + gblk*16 + 4*g + 3] : 0.0f;
      pk[g] = pack4_fp8(v0, v1, v2, v3);
    }
    int dst = row*256 + ((gblk*16) ^ ((row&7)<<4));
    *reinterpret_cast<uint4*>(&Ahl[0][dst]) = *reinterpret_cast<const uint4*>(pk);
  }
  int cb = 16*w + (l & 15);                // this lane's unit (0..255)
  int arow = l & 15;
  // c state: lane owns unit cb, batches (l>>4)*4+r
  float creg[4];
  #pragma unroll
  for (int r = 0; r < 4; r++)
    creg[r] = c0 ? c0[(size_t)(g0*16 + (l>>4)*4 + r)*256 + cb] : 0.0f;

  // t-invariant addresses, kept live in registers
  int aoff[8], b0off[8], b1off[8];
  #pragma unroll
  for (int k0 = 0; k0 < 8; k0++){
    int kb = k0*32 + ((l>>4)*8);
    aoff[k0]  = arow*256 + (kb ^ ((arow&7)<<4));
    b0off[k0] = cb*256 + (kb ^ ((cb&7)<<4));
    b1off[k0] = (256+cb)*256 + (kb ^ ((cb&7)<<4));
  }
  const unsigned char* wg2 = Wt + (size_t)(512+cb)*256 + ((l>>4)*8);
  const unsigned char* wg3 = Wt + (size_t)(768+cb)*256 + ((l>>4)*8);
  int astore[4];
  const float* xb[4];
  float* hp[4];
  #pragma unroll
  for (int r = 0; r < 4; r++){
    int batch = (l>>4)*4 + r;
    astore[r] = batch*256 + ((cb & 0xF0) ^ ((batch&7)<<4)) + (cb & 15);
    xb[r] = xW + (size_t)(g0*16 + batch)*1024 + cb;
    hp[r] = Hout + (size_t)(g0*16 + batch)*NT*256 + cb;
  }
  __syncthreads();

  // prefetch t=0 xW into registers
  float xn[4][4];
  #pragma unroll
  for (int gt = 0; gt < 4; gt++)
    #pragma unroll
    for (int r = 0; r < 4; r++)
      xn[gt][r] = xb[r][gt*256];

  for (int t = 0; t < NT; t++){
    int cur = t & 1, nxt = cur ^ 1;
    // acc init = prefetched xW (MFMA C-in); [gate]
    f32x4 acc[4];
    #pragma unroll
    for (int gt = 0; gt < 4; gt++)
      #pragma unroll
      for (int r = 0; r < 4; r++)
        acc[gt][r] = xn[gt][r];
    // issue next step's xW loads now; they retire under the K-loop + cell
    if (t + 1 < NT){
      #pragma unroll
      for (int r = 0; r < 4; r++) xb[r] += B_*1024;
      #pragma unroll
      for (int gt = 0; gt < 4; gt++)
        #pragma unroll
        for (int r = 0; r < 4; r++)
          xn[gt][r] = xb[r][gt*256];
    }
    // K loop: 8 x 32
    const unsigned char* Ac = Ahl[cur];
    #pragma unroll
    for (int k0 = 0; k0 < 8; k0++){
      long long afr = *reinterpret_cast<const long long*>(Ac + aoff[k0]);
      long long b0 = *reinterpret_cast<const long long*>(Wl + b0off[k0]);
      long long b1 = *reinterpret_cast<const long long*>(Wl + b1off[k0]);
      long long b2 = *reinterpret_cast<const long long*>(wg2 + k0*32);
      long long b3 = *reinterpret_cast<const long long*>(wg3 + k0*32);
      acc[0] = __builtin_amdgcn_mfma_f32_16x16x32_fp8_fp8(afr, b0, acc[0], 0, 0, 0);
      acc[1] = __builtin_amdgcn_mfma_f32_16x16x32_fp8_fp8(afr, b1, acc[1], 0, 0, 0);
      acc[2] = __builtin_amdgcn_mfma_f32_16x16x32_fp8_fp8(afr, b2, acc[2], 0, 0, 0);
      acc[3] = __builtin_amdgcn_mfma_f32_16x16x32_fp8_fp8(afr, b3, acc[3], 0, 0, 0);
    }
    // cell update (C/D layout: col=l&15, row=(l>>4)*4+r) — 4 cells/lane
    #pragma unroll
    for (int r = 0; r < 4; r++){
      float vi = acc[0][r], vf = acc[1][r];
      float vg = acc[2][r], vo = acc[3][r];
      float cn = d_sig(vf)*creg[r] + d_sig(vi)*d_tanh(vg);
      float hn = d_sig(vo)*d_tanh(cn);
      creg[r] = cn;
      Ahl[nxt][astore[r]] = f2fp8_b(hn);
      hp[r][0] = hn;
      hp[r] += 256;
    }
    __syncthreads();   // Ahl[nxt] complete before next step's reads
  }
}

// ---------------- phi = enc_out @ crf_W + b  (time-major [t][b][k])
__global__ __launch_bounds__(256) void k_phi(const float* __restrict__ H,
    const float* __restrict__ Wc, const float* __restrict__ bc,
    float* __restrict__ phi){
  __shared__ float sH[8][256];
  int tid = threadIdx.x; int rl = tid >> 5, j = tid & 31;
  int r0 = blockIdx.x*8;
  for (int i = tid; i < 512; i += 256){
    int rr = i >> 6, c4 = i & 63;
    *reinterpret_cast<float4*>(&sH[rr][c4*4]) =
      *reinterpret_cast<const float4*>(&H[(size_t)(r0+rr)*256 + c4*4]);
  }
  __syncthreads();
  int r = r0 + rl;                    // r = b*128 + t
  int b = r >> 7, t = r & 127;
  float acc = bc[j];
  #pragma unroll 4
  for (int d = 0; d < 256; d++) acc += sH[rl][d]*Wc[d*K_ + j];
  phi[(size_t)t*B_*K_ + b*K_ + j] = acc;
}

// ---------------- fused z_logits + lpz (LDS row staging)
__global__ __launch_bounds__(256) void k_zlp(const float* __restrict__ A,
    const float* __restrict__ Wz, const float* __restrict__ bz,
    const int* __restrict__ zids, float* __restrict__ lpz){
  __shared__ float sA[8][256];
  int tid = threadIdx.x; int rl = tid >> 5, j = tid & 31;
  int r0 = blockIdx.x*8;
  for (int i = tid; i < 512; i += 256){
    int rr = i >> 6, c4 = i & 63;
    *reinterpret_cast<float4*>(&sA[rr][c4*4]) =
      *reinterpret_cast<const float4*>(&A[(size_t)(r0+rr)*256 + c4*4]);
  }
  __syncthreads();
  int r = r0 + rl;
  float acc = bz[j];
  #pragma unroll 4
  for (int d = 0; d < 256; d++) acc += sA[rl][d]*Wz[d*K_ + j];
  float m = acc;
  #pragma unroll
  for (int off=16; off; off>>=1) m = fmaxf(m, __shfl_xor(m, off, 32));
  float e = __expf(acc - m), E = e;
  #pragma unroll
  for (int off=16; off; off>>=1) E += __shfl_xor(E, off, 32);
  int b = r / TD_, t = r - b*TD_;
  int tz = zids[b*T_ + t + 1];
  float vtz = __shfl(acc, tz, 32);
  if (j == 0) lpz[r] = vtz - (m + logf(E));
}

// ---------------- CRF forward scan + entropy (double-buffered, 1 barrier/step)
__global__ __launch_bounds__(1024) void k_crf(
    const float* __restrict__ phi, const float* __restrict__ trans,
    const int* __restrict__ lens, float* __restrict__ alphas,
    float* __restrict__ ent_b){
  __shared__ float sal[2][K_], sH[2][K_];
  int tid = threadIdx.x, b = blockIdx.x;
  int i = tid & 31, j = tid >> 5;
  float tr = trans[i*K_ + j];
  int len = lens[b];
  if (tid < K_){
    float a0 = phi[b*K_ + tid] + phi[(size_t)B_*K_ + b*K_ + tid];  // raw0+raw1
    sal[0][tid] = a0; sH[0][tid] = 0.0f;
    alphas[b*K_ + tid] = a0;
  }
  __syncthreads();
  for (int t = 1; t < T_; t++){
    int cur = (t-1) & 1, nxt = t & 1;
    bool active = (t < len);
    float ai = sal[cur][i], Hi = sH[cur][i];
    float aj = sal[cur][j], Hj = sH[cur][j];
    float s = ai + tr;
    float m = s;
    #pragma unroll
    for (int off=16; off; off>>=1) m = fmaxf(m, __shfl_xor(m, off, 32));
    float e = expf(s - m);
    float E = e;
    #pragma unroll
    for (int off=16; off; off>>=1) E += __shfl_xor(E, off, 32);
    float lZ = m + logf(E);
    float w = e / E;
    float logw = s - lZ;
    float nH = w * (Hi - logw);
    #pragma unroll
    for (int off=16; off; off>>=1) nH += __shfl_xor(nH, off, 32);
    float pm = phi[(size_t)(t-1)*B_*K_ + b*K_ + j];
    float pt = phi[(size_t)t*B_*K_ + b*K_ + j];
    float ps = (t == T_-1) ? (pm + 2.0f*pt)
                           : (pm + 2.0f*pt + phi[(size_t)(t+1)*B_*K_ + b*K_ + j]);
    float na = lZ + ps;
    float outa = active ? na : aj;
    float outH = active ? nH : Hj;
    if (i == 0){
      sal[nxt][j] = outa; sH[nxt][j] = outH;
      alphas[(size_t)t*B_*K_ + b*K_ + j] = outa;
    }
    __syncthreads();
  }
  int fb = (T_-1) & 1;
  if (tid < K_){
    float a = sal[fb][tid];
    float m = a;
    #pragma unroll
    for (int off=16; off; off>>=1) m = fmaxf(m, __shfl_xor(m, off, 32));
    float e = expf(a-m), E = e;
    #pragma unroll
    for (int off=16; off; off>>=1) E += __shfl_xor(E, off, 32);
    float lse = m + logf(E);
    float lp = a - lse;
    float v = expf(lp)*(sH[fb][tid]-lp);
    #pragma unroll
    for (int off=16; off; off>>=1) v += __shfl_xor(v, off, 32);
    if (tid == 0) ent_b[b] = v;
  }
}

// ---------------- backward Gumbel sampler
__global__ void k_sampler(const float* __restrict__ alphas, const float* __restrict__ trans,
                          const float* __restrict__ gum, const int* __restrict__ lens,
                          const float* __restrict__ tau_p,
                          float* __restrict__ y_all, int* __restrict__ z_ids){
  int b = blockIdx.x;
  int lane = threadIdx.x;
  int k = lane & 31;
  float inv_tau = d_rcp(tau_p[0]);
  int len = lens[b];
  int nid = 0;
  for (int t = T_-1; t >= 0; t--){
    bool active  = (t < len);
    bool is_last = (t == len-1);
    float a = alphas[(size_t)t*B_*K_ + b*K_ + k];
    float lg = is_last ? a : a + trans[k*K_ + nid];
    float val = (lg + gum[(size_t)t*B_*K_ + b*K_ + k]) * inv_tau;
    float m = val;
    #pragma unroll
    for (int off=16; off; off>>=1) m = fmaxf(m, __shfl_xor(m, off, 32));
    float e = expf(val - m), E = e;
    #pragma unroll
    for (int off=16; off; off>>=1) E += __shfl_xor(E, off, 32);
    float y = active ? e*d_rcp(E) : 0.0f;
    if (lane < K_) y_all[(size_t)(b*T_ + t)*K_ + k] = y;
    float bv = val; int bk = k;
    #pragma unroll
    for (int off=16; off; off>>=1){
      float ov = __shfl_xor(bv, off, 32);
      int   ok = __shfl_xor(bk, off, 32);
      if (ov > bv || (ov == bv && ok < bk)){ bv = ov; bk = ok; }
    }
    int ids = active ? bk : 0;
    nid = ids;
    if (lane == 0) z_ids[b*T_ + t] = ids;
  }
}

// ---------------- attention 1
__global__ __launch_bounds__(256) void k_attn1(
    const float* __restrict__ q, const float* __restrict__ memk,
    const float* __restrict__ kv_emb, const int* __restrict__ keys,
    const float* __restrict__ av, float* __restrict__ ctx){
  __shared__ float se[16];
  int r = blockIdx.x, tid = threadIdx.x;
  int b = r / TD_;
  int m = tid >> 4, ds = tid & 15;
  float p = 0.0f;
  #pragma unroll 4
  for (int qq = 0; qq < 16; qq++){
    int dd = ds + qq*16;
    p += d_tanh(q[(size_t)r*256 + dd] + memk[(size_t)(b*M_+m)*256 + dd]) * av[dd];
  }
  #pragma unroll
  for (int off=8; off; off>>=1) p += __shfl_xor(p, off, 16);
  if (ds == 0) se[m] = (keys[b*M_+m] != 0) ? p : -1e9f;
  __syncthreads();
  float mx = -1e30f;
  #pragma unroll
  for (int mm=0;mm<16;mm++) mx = fmaxf(mx, se[mm]);
  float den = 0.0f, ex[16];
  #pragma unroll
  for (int mm=0;mm<16;mm++){ ex[mm] = __expf(se[mm]-mx); den += ex[mm]; }
  float cacc = 0.0f;
  #pragma unroll
  for (int mm=0;mm<16;mm++) cacc += ex[mm]*kv_emb[(size_t)(b*M_+mm)*256 + tid];
  ctx[(size_t)r*256 + tid] = cacc*d_rcp(den);
}

// ---------------- attention 2 + copy + gate
__global__ __launch_bounds__(256) void k_attn2g(
    const float* __restrict__ q2, const float* __restrict__ dint,
    const float* __restrict__ memk2, const int* __restrict__ keys,
    const float* __restrict__ cv, const float* __restrict__ gW, const float* __restrict__ gb,
    const int* __restrict__ sent,
    float* __restrict__ cpx, float* __restrict__ gsig){
  __shared__ float se2[16];
  __shared__ float sred[4];
  int r = blockIdx.x, tid = threadIdx.x;
  int b = r / TD_, t = r - b*TD_;
  int m = tid >> 4, ds = tid & 15;
  float p = 0.0f;
  #pragma unroll 4
  for (int qq = 0; qq < 16; qq++){
    int dd = ds + qq*16;
    p += d_tanh(q2[(size_t)r*256 + dd] + memk2[(size_t)(b*M_+m)*256 + dd]) * cv[dd];
  }
  #pragma unroll
  for (int off=8; off; off>>=1) p += __shfl_xor(p, off, 16);
  if (ds == 0) se2[m] = (keys[b*M_+m] != 0) ? p : -1e9f;
  float gp = dint[(size_t)r*256 + tid]*gW[tid];
  #pragma unroll
  for (int off=32; off; off>>=1) gp += __shfl_xor(gp, off, 64);
  if ((tid & 63) == 0) sred[tid>>6] = gp;
  __syncthreads();
  if (tid == 0){
    float mx = -1e30f;
    #pragma unroll
    for (int mm=0;mm<16;mm++) mx = fmaxf(mx, se2[mm]);
    float den = 0.0f, ex[16];
    #pragma unroll
    for (int mm=0;mm<16;mm++){ ex[mm] = __expf(se2[mm]-mx); den += ex[mm]; }
    int txi = sent[b*T_ + t + 1];
    float idn = d_rcp(den);
    float cp = 0.0f;
    #pragma unroll
    for (int mm=0;mm<16;mm++) if (keys[b*M_+mm] == txi) cp += ex[mm]*idn;
    cpx[r] = cp;
    gsig[r] = d_sig(sred[0]+sred[1]+sred[2]+sred[3] + gb[0]);
  }
}

// ---------------- dint -> packed fp8 (pack ONCE; bit-identical)
__global__ void k_a8(const float* __restrict__ dint, unsigned* __restrict__ A8){
  int idx = blockIdx.x*256 + threadIdx.x;   // R_*64 u32s
  if (idx >= R_*64) return;
  float4 f = *reinterpret_cast<const float4*>(dint + (size_t)idx*4);
  A8[idx] = pack4_fp8(f.x, f.y, f.z, f.w);
}

// ---------------- fp8 MFMA GEMM + online LSE over V (r25-EXACT: 256-row A
// tile, single W buffer, 80KB LDS -> 2 blocks/CU. r22's 96KB dbuf lost
// occupancy; r26's 64KB half-tile dbuf lost W-reuse. This shape is the
// certified local optimum.)
__global__ __launch_bounds__(512) void k_lse8(
    const unsigned char* __restrict__ A8,   // dint fp8 [R][256] bytes
    const unsigned char* __restrict__ Wt8,  // [V][256] fp8
    const float* __restrict__ bias,
    float* __restrict__ part){              // [R][NCH_][2]
  __shared__ unsigned char Al[256*256];     // 64KB, swizzled fp8
  __shared__ unsigned char Wl[64*256];      // 16KB, swizzled fp8
  int tid = threadIdx.x;
  int row0 = blockIdx.x*256;
  #pragma unroll
  for (int q = 0; q < 8; q++){
    int u = tid + q*512;
    int row = u >> 4, s16 = u & 15;
    int r = row0 + row;
    uint4 pk = (uint4){0u,0u,0u,0u};
    if (r < R_)
      pk = *reinterpret_cast<const uint4*>(A8 + (size_t)r*256 + s16*16);
    int dst = row*256 + ((s16*16) ^ ((row&7)<<4));
    *reinterpret_cast<uint4*>(&Al[dst]) = pk;
  }
  __syncthreads();
  int w = tid >> 6, l = tid & 63;
  int arow = 16*w + (l & 15);
  long long afrA[8], afrB[8];
  #pragma unroll
  for (int k0 = 0; k0 < 8; k0++){
    int kb = k0*32 + ((l>>4)*8);
    afrA[k0] = *reinterpret_cast<const long long*>(&Al[arow*256 + (kb ^ ((arow&7)<<4))]);
    int ar2 = arow + 128;
    afrB[k0] = *reinterpret_cast<const long long*>(&Al[ar2*256 + (kb ^ ((ar2&7)<<4))]);
  }
  float rm[2][4], rs[2][4];                 // per-lane over its 4-col slice
  #pragma unroll
  for (int rf=0;rf<2;rf++)
    #pragma unroll
    for (int r4=0;r4<4;r4++){ rm[rf][r4] = -3.0e38f; rs[rf][r4] = 0.0f; }

  for (int ct = blockIdx.y; ct < 500; ct += NCH_){
    int col0 = ct*64;
    __syncthreads();
    #pragma unroll
    for (int q = 0; q < 2; q++){
      int u = tid + q*512;
      int c = u >> 4, s16 = u & 15;
      int dst = c*256 + ((s16*16) ^ ((c&7)<<4));
      *reinterpret_cast<uint4*>(&Wl[dst]) =
        *reinterpret_cast<const uint4*>(&Wt8[(size_t)(col0+c)*256 + s16*16]);
    }
    __syncthreads();
    f32x4 acc[2][4];
    #pragma unroll
    for (int rf=0;rf<2;rf++)
      #pragma unroll
      for (int nf=0;nf<4;nf++) acc[rf][nf] = (f32x4){0.f,0.f,0.f,0.f};
    #pragma unroll
    for (int k0 = 0; k0 < 8; k0++){
      int kb = k0*32 + ((l>>4)*8);
      #pragma unroll
      for (int nf = 0; nf < 4; nf++){
        int bc = nf*16 + (l & 15);
        long long bfr = *reinterpret_cast<const long long*>(&Wl[bc*256 + (kb ^ ((bc&7)<<4))]);
        acc[0][nf] = __builtin_amdgcn_mfma_f32_16x16x32_fp8_fp8(afrA[k0], bfr, acc[0][nf], 0, 0, 0);
        acc[1][nf] = __builtin_amdgcn_mfma_f32_16x16x32_fp8_fp8(afrB[k0], bfr, acc[1][nf], 0, 0, 0);
      }
    }
    float bb[4];
    #pragma unroll
    for (int nf=0;nf<4;nf++) bb[nf] = bias[col0 + nf*16 + (l&15)];
    #pragma unroll
    for (int rf = 0; rf < 2; rf++){
      #pragma unroll
      for (int r4 = 0; r4 < 4; r4++){
        float v0 = acc[rf][0][r4]+bb[0], v1 = acc[rf][1][r4]+bb[1];
        float v2 = acc[rf][2][r4]+bb[2], v3 = acc[rf][3][r4]+bb[3];
        float tm = fmaxf(fmaxf(v0,v1), fmaxf(v2,v3));
        float ts = __expf(v0-tm)+__expf(v1-tm)+__expf(v2-tm)+__expf(v3-tm);
        float m0 = rm[rf][r4];
        if (tm <= m0){
          rs[rf][r4] += ts*__expf(tm - m0);
        } else {
          rs[rf][r4] = rs[rf][r4]*__expf(m0 - tm) + ts;
          rm[rf][r4] = tm;
        }
      }
    }
  }
  // one-time 16-lane row-group combine (exact same part[] semantics)
  #pragma unroll
  for (int rf = 0; rf < 2; rf++){
    #pragma unroll
    for (int r4 = 0; r4 < 4; r4++){
      float M = rm[rf][r4];
      #pragma unroll
      for (int off=8; off; off>>=1) M = fmaxf(M, __shfl_xor(M, off, 16));
      float S = rs[rf][r4]*__expf(rm[rf][r4] - M);
      #pragma unroll
      for (int off=8; off; off>>=1) S += __shfl_xor(S, off, 16);
      if ((l & 15) == 0){
        int grow = row0 + rf*128 + 16*w + (l>>4)*4 + r4;
        if (grow < R_){
          part[((size_t)grow*NCH_ + blockIdx.y)*2 + 0] = M;
          part[((size_t)grow*NCH_ + blockIdx.y)*2 + 1] = S;
        }
      }
    }
  }
}

__global__ void k_lse_combine(const float* __restrict__ part, float* __restrict__ lse){
  int r = blockIdx.x*256 + threadIdx.x;
  if (r >= R_) return;
  float M = -3.0e38f;
  for (int c = 0; c < NCH_; c++) M = fmaxf(M, part[((size_t)r*NCH_+c)*2]);
  float S = 0.0f;
  for (int c = 0; c < NCH_; c++){
    float m = part[((size_t)r*NCH_+c)*2], s = part[((size_t)r*NCH_+c)*2+1];
    S += s*__expf(m - M);
  }
  lse[r] = M + logf(S);
}

// target logit from the SAME quantized weights/activations as the LSE
__global__ __launch_bounds__(256) void k_ltx(const unsigned char* __restrict__ A8,
    const unsigned char* __restrict__ Wt8, const float* __restrict__ bias,
    const int* __restrict__ sent, float* __restrict__ out){
  int tid = threadIdx.x;
  int r = blockIdx.x*4 + (tid >> 6);
  int lane = tid & 63;
  int b = r / TD_, t = r - b*TD_;
  int tx = sent[b*T_ + t + 1];
  unsigned wq = *reinterpret_cast<const unsigned*>(Wt8 + (size_t)tx*256 + lane*4);
  float wv[4]; cvt4_fp8(wq, wv);
  unsigned aq = *reinterpret_cast<const unsigned*>(A8 + (size_t)r*256 + lane*4);
  float av[4]; cvt4_fp8(aq, av);
  float acc = av[0]*wv[0] + av[1]*wv[1] + av[2]*wv[2] + av[3]*wv[3];
  #pragma unroll
  for (int off=32; off; off>>=1) acc += __shfl_xor(acc, off, 64);
  if (lane == 0) out[r] = acc + bias[tx];
}

__global__ __launch_bounds__(256) void k_final(
    const float* __restrict__ lse, const float* __restrict__ ltx,
    const float* __restrict__ gsig, const float* __restrict__ cpx,
    const float* __restrict__ lpz, const float* __restrict__ ent_b,
    const int* __restrict__ lens, float* __restrict__ out){
  __shared__ float sred[256];
  int tid = threadIdx.x;
  float sum = 0.0f;
  for (int r = tid; r < R_; r += 256){
    int b = r / TD_, t = r % TD_;
    if (t < lens[b]){
      float g = gsig[r];
      float lm = __expf(ltx[r] - lse[r]);
      float p = (1.0f-g)*lm + g*cpx[r] + 1e-10f;
      sum += logf(p) + lpz[r];
    }
  }
  sred[tid] = sum;
  __syncthreads();
  for (int s = 128; s; s >>= 1){ if (tid < s) sred[tid] += sred[tid+s]; __syncthreads(); }
  if (tid == 0){
    float es = 0.0f, dn = 0.0f;
    for (int b = 0; b < B_; b++){ es += ent_b[b]; dn += (float)lens[b]; }
    out[0] = -( es/(float)B_ + sred[0]/dn );
  }
}

} // anonymous namespace

extern "C" void kernel_launch(void* const* d_in, const int* in_sizes, int n_in,
                              void* d_out, int out_size, void* d_ws, size_t ws_size,
                              hipStream_t stream){
  const int*   keys  = (const int*)d_in[0];
  const int*   vals  = (const int*)d_in[1];
  const int*   sent  = (const int*)d_in[2];
  const int*   lens  = (const int*)d_in[3];
  const float* tau   = (const float*)d_in[4];
  const float* xl    = (const float*)d_in[5];
  const float* gum   = (const float*)d_in[6];
  const float* drop  = (const float*)d_in[7];
  const float* emb   = (const float*)d_in[8];
  const float* z_emb = (const float*)d_in[9];
  const float* eWih  = (const float*)d_in[10];
  const float* eWhh  = (const float*)d_in[11];
  const float* eb    = (const float*)d_in[12];
  const float* crfW  = (const float*)d_in[13];
  const float* crfb  = (const float*)d_in[14];
  const float* trans = (const float*)d_in[15];
  const float* iWh   = (const float*)d_in[16];
  const float* ibh   = (const float*)d_in[17];
  const float* iWc   = (const float*)d_in[18];
  const float* ibc   = (const float*)d_in[19];
  const float* dWih  = (const float*)d_in[20];
  const float* dWhh  = (const float*)d_in[21];
  const float* db    = (const float*)d_in[22];
  const float* aWq   = (const float*)d_in[23];
  const float* aWk   = (const float*)d_in[24];
  const float* av    = (const float*)d_in[25];
  const float* aoW   = (const float*)d_in[26];
  const float* aob   = (const float*)d_in[27];
  const float* pzW   = (const float*)d_in[28];
  const float* pzb   = (const float*)d_in[29];
  const float* intW  = (const float*)d_in[30];
  const float* intb  = (const float*)d_in[31];
  const float* outW  = (const float*)d_in[32];
  const float* outb  = (const float*)d_in[33];
  const float* cWq   = (const float*)d_in[34];
  const float* cWk   = (const float*)d_in[35];
  const float* cv    = (const float*)d_in[36];
  const float* gW    = (const float*)d_in[37];
  const float* gb    = (const float*)d_in[38];
  (void)in_sizes; (void)n_in; (void)out_size; (void)ws_size;

  float* ws = (float*)d_ws;
  size_t o = 0;
  auto alloc = [&](size_t n){ size_t r = o; o += (n + 3) & ~(size_t)3; return r; };
  float* sent_emb = ws + alloc((size_t)B_*T_*D_);
  float* kv_emb   = ws + alloc((size_t)B_*M_*D_);
  float* kv_enc   = ws + alloc((size_t)B_*D_);
  float* h0       = ws + alloc((size_t)B_*D_);
  float* c0       = ws + alloc((size_t)B_*D_);
  float* memk     = ws + alloc((size_t)B_*M_*D_);
  float* memk2    = ws + alloc((size_t)B_*M_*D_);
  float* xW       = ws + alloc((size_t)B_*T_*D4_);
  float* encH     = ws + alloc((size_t)B_*T_*D_);
  float* phi_raw  = ws + alloc((size_t)T_*B_*K_);
  float* alphas   = ws + alloc((size_t)T_*B_*K_);
  float* ent_b    = ws + alloc((size_t)B_);
  float* y_all    = ws + alloc((size_t)B_*T_*K_);
  float* zse      = ws + alloc((size_t)B_*T_*D_);
  float* qbuf     = ws + alloc((size_t)R_*D_);
  float* ctx      = ws + alloc((size_t)R_*D_);
  float* dec_out  = ws + alloc((size_t)R_*D_);
  float* dint     = ws + alloc((size_t)R_*D_);
  float* lpz_b    = ws + alloc((size_t)R_);
  float* gsig     = ws + alloc((size_t)R_);
  float* cpx      = ws + alloc((size_t)R_);
  float* ltx      = ws + alloc((size_t)R_);
  float* lse      = ws + alloc((size_t)R_);
  float* part     = ws + alloc((size_t)R_*NCH_*2);
  int*   z_ids    = (int*)(ws + alloc((size_t)B_*T_));
  unsigned* A8    = (unsigned*)(ws + alloc((size_t)R_*64));
  unsigned char* WhhT8E = (unsigned char*)(ws + alloc((size_t)D4_*D_/4));
  unsigned char* WhhT8D = (unsigned char*)(ws + alloc((size_t)D4_*D_/4));
  unsigned char* Wt8    = (unsigned char*)(ws + alloc((size_t)V_*D_/4));
  unsigned short* eWihT = (unsigned short*)(ws + alloc((size_t)D4_*D_/2));
  unsigned short* dWihT = (unsigned short*)(ws + alloc((size_t)D4_*D_/2));
  unsigned short* aWqT  = (unsigned short*)(ws + alloc((size_t)D_*D_/2));
  unsigned short* cWqT  = (unsigned short*)(ws + alloc((size_t)D_*D_/2));
  unsigned short* aoWtT = (unsigned short*)(ws + alloc((size_t)D_*D_/2));
  unsigned short* aoWbT = (unsigned short*)(ws + alloc((size_t)D_*D_/2));
  unsigned short* inWtT = (unsigned short*)(ws + alloc((size_t)D_*D_/2));
  unsigned short* inWbT = (unsigned short*)(ws + alloc((size_t)D_*D_/2));

  float* Hdec = encH;   // alias: enc_out dead after k_phi

  // prep (fused launches)
  k_emb2<<<B_*T_ + B_*M_, 256, 0, stream>>>(sent, keys, vals, emb, sent_emb, kv_emb);
  k_kv_enc<<<B_*D_/256, 256, 0, stream>>>(keys, kv_emb, kv_enc);
  k_rowgemm2<<<B_, 256, 0, stream>>>(kv_enc, iWh, ibh, h0, iWc, ibc, c0, 256, 256);
  k_rowgemm2<<<B_*M_, 256, 0, stream>>>(kv_emb, aWk, nullptr, memk,
                                        cWk, nullptr, memk2, 256, 256);
  k_wt8_2<<<32, 256, 0, stream>>>(eWhh, dWhh, WhhT8E, WhhT8D, D4_);
  k_wt8<<<V_/64, 256, 0, stream>>>(outW, Wt8, V_);
  k_wtg2<<<32, 256, 0, stream>>>(eWih, dWih, eWihT, dWihT, D4_);
  k_wtg6<<<24, 256, 0, stream>>>(aWq, cWq, aoW, aoW + 256*256, intW, intW + 256*256,
                                 aWqT, cWqT, aoWtT, aoWbT, inWtT, inWbT);

  // encoder (xW written time-major [t][B][1024] via TMD=T_)
  k_gemm<0,0,1,4,true,T_><<<dim3(B_*T_/128, 4), 512, 0, stream>>>(
      sent_emb, nullptr, eWihT, nullptr, eb, xW, D4_, nullptr, nullptr);
  k_lstm12<<<B_/16, 1024, 0, stream>>>(xW, WhhT8E, nullptr, nullptr, encH, T_);
  k_phi<<<B_*T_/8, 256, 0, stream>>>(encH, crfW, crfb, phi_raw);
  k_crf<<<B_, 1024, 0, stream>>>(phi_raw, trans, lens, alphas, ent_b);
  k_sampler<<<B_, 64, 0, stream>>>(alphas, trans, gum, lens, tau, y_all, z_ids);
  k_rowgemm<<<B_*T_, 256, 0, stream>>>(y_all, z_emb, nullptr, zse, K_, 256);

  // decoder inputs (time-major via TMD=TD_) + scan
  k_gemm<1,0,1,4,true,TD_><<<dim3(R_/128, 4), 512, 0, stream>>>(
      sent_emb, zse, dWihT, nullptr, db, xW, D4_, drop, xl);
  k_lstm12<<<B_/16, 1024, 0, stream>>>(xW, WhhT8D, h0, c0, Hdec, TD_);

  // decoder post-processing (parallel over R rows)
  k_gemm<0,0,1,1,false,0><<<dim3(R_/128, 4), 512, 0, stream>>>(
      Hdec, nullptr, aWqT, nullptr, nullptr, qbuf, D_, nullptr, nullptr);
  k_attn1<<<R_, 256, 0, stream>>>(qbuf, memk, kv_emb, keys, av, ctx);
  k_gemm<0,0,2,1,true,0><<<dim3(R_/128, 4), 512, 0, stream>>>(
      Hdec, ctx, aoWtT, aoWbT, aob, dec_out, D_, nullptr, nullptr);
  k_zlp<<<R_/8, 256, 0, stream>>>(dec_out, pzW, pzb, z_ids, lpz_b);
  k_gemm<0,2,2,1,true,0><<<dim3(R_/128, 4), 512, 0, stream>>>(
      dec_out, zse, inWtT, inWbT, intb, dint, D_, nullptr, nullptr);
  k_a8<<<(R_*64+255)/256, 256, 0, stream>>>(dint, A8);
  k_gemm<0,0,1,1,false,0><<<dim3(R_/128, 4), 512, 0, stream>>>(
      dint, nullptr, cWqT, nullptr, nullptr, qbuf, D_, nullptr, nullptr);
  k_attn2g<<<R_, 256, 0, stream>>>(qbuf, dint, memk2, keys, cv, gW, gb, sent,
                                   cpx, gsig);

  // vocab LSE (fp8 MFMA) + target logit + loss
  k_lse8<<<dim3((R_+255)/256, NCH_), 512, 0, stream>>>(
      (const unsigned char*)A8, Wt8, outb, part);
  k_lse_combine<<<(R_+255)/256, 256, 0, stream>>>(part, lse);
  k_ltx<<<R_/4, 256, 0, stream>>>((const unsigned char*)A8, Wt8, outb, sent, ltx);
  k_final<<<1, 256, 0, stream>>>(lse, ltx, gsig, cpx, lpz_b, ent_b, lens, (float*)d_out);
}